// Round 1
// baseline (646.400 us; speedup 1.0000x reference)
//
#include <hip/hip_runtime.h>
#include <math.h>

#define BB 16
#define C_IN 256
#define HH 112
#define WW 112
#define ID 64
#define HSZ 28
#define NN 784
#define NQ (BB*NN*ID)   // 802816 floats per [B,N,64] buffer

// ---------------- Kernel 1: pool (max+avg) + 4 fused GEMVs -> k1,v1,k2,v2 ----------------
__global__ __launch_bounds__(256) void kpool(const float* __restrict__ x,
    const float* __restrict__ k1w, const float* __restrict__ v1w,
    const float* __restrict__ k2w, const float* __restrict__ v2w,
    float* __restrict__ k1, float* __restrict__ v1,
    float* __restrict__ k2, float* __restrict__ v2)
{
    __shared__ float ms[4][256];
    __shared__ float as[4][256];
    int blk = blockIdx.x;
    int b  = blk / 196;
    int r1 = blk % 196;
    int hs = r1 / 7;
    int wg = r1 % 7;        // 4 ws positions per block: ws = 4*wg + j
    int t = threadIdx.x;
    {
        int c = t;  // 256 threads = 256 channels
        const float* base = x + (((size_t)(b*C_IN + c)*HH) + hs*4)*WW + wg*16;
        float m[4], s[4];
        #pragma unroll
        for (int j=0;j<4;j++){ m[j] = -3.4e38f; s[j]=0.f; }
        #pragma unroll
        for (int r=0;r<4;r++){
            const float4* rp = (const float4*)(base + r*WW);
            #pragma unroll
            for (int j=0;j<4;j++){
                float4 v = rp[j];
                m[j] = fmaxf(m[j], fmaxf(fmaxf(v.x,v.y), fmaxf(v.z,v.w)));
                s[j] += (v.x+v.y)+(v.z+v.w);
            }
        }
        #pragma unroll
        for (int j=0;j<4;j++){ ms[j][c]=m[j]; as[j][c]=s[j]*(1.f/16.f); }
    }
    __syncthreads();
    int wsj = t >> 6, o = t & 63;
    float a1=0.f,a2=0.f,a3=0.f,a4=0.f;
    for (int c=0;c<256;c++){
        float mv = ms[wsj][c], av = as[wsj][c];
        a1 = fmaf(mv, k1w[c*64+o], a1);
        a2 = fmaf(mv, v1w[c*64+o], a2);
        a3 = fmaf(av, k2w[c*64+o], a3);
        a4 = fmaf(av, v2w[c*64+o], a4);
    }
    int n = hs*28 + wg*4 + wsj;
    size_t idx = ((size_t)(b*NN + n))*64 + o;
    k1[idx]=a1; v1[idx]=a2; k2[idx]=a3; v2[idx]=a4;
}

// ---------------- Kernel 2: strided conv (patch embed) + LayerNorm + q GEMV ----------------
__global__ __launch_bounds__(256) void kconv(const float* __restrict__ x,
    const float* __restrict__ srw, const float* __restrict__ srb,
    const float* __restrict__ lng, const float* __restrict__ lnb,
    const float* __restrict__ qw, float* __restrict__ q)
{
    __shared__ float win[32*4*112];   // 14336 floats; reused for qn (1792) later
    int blk = blockIdx.x;
    int b = blk / 28, hs = blk % 28;
    int t = threadIdx.x;
    int ng = t >> 6, o = t & 63;      // thread owns output-channel o, ws = ng+4j
    float acc[7];
    #pragma unroll
    for (int j=0;j<7;j++) acc[j]=0.f;

    for (int c0=0;c0<256;c0+=32){
        __syncthreads();
        for (int li = t; li < 3584; li += 256){
            int cr = li / 28, f = li % 28;   // cr = c*4+r
            int c = cr >> 2, r = cr & 3;
            const float4* src = (const float4*)(x + (((size_t)(b*C_IN + c0 + c)*HH) + hs*4 + r)*WW) + f;
            ((float4*)win)[cr*28 + f] = *src;
        }
        __syncthreads();
        for (int c=0;c<32;c++){
            const float* wrow = srw + ((size_t)o)*4096 + (size_t)(c0+c)*16;
            const float* xrow = win + c*448;
            #pragma unroll
            for (int r=0;r<4;r++){
                float4 w4 = ((const float4*)wrow)[r];
                const float* xr = xrow + r*112;
                #pragma unroll
                for (int j=0;j<7;j++){
                    int col = (ng + 4*j)*4;
                    float s = xr[col]*w4.x + xr[col+1]*w4.y;
                    s += xr[col+2]*w4.z + xr[col+3]*w4.w;
                    acc[j] += s;
                }
            }
        }
    }
    float bias = srb[o];
    float g = lng[o], be = lnb[o];
    float qn[7];
    #pragma unroll
    for (int j=0;j<7;j++){
        float v = acc[j] + bias;
        float s = v, ss = v*v;
        #pragma unroll
        for (int off=1; off<64; off<<=1){
            s  += __shfl_xor(s, off, 64);
            ss += __shfl_xor(ss, off, 64);
        }
        float mu  = s*(1.f/64.f);
        float var = ss*(1.f/64.f) - mu*mu;
        qn[j] = (v - mu) * rsqrtf(var + 1e-5f) * g + be;
    }
    __syncthreads();
    #pragma unroll
    for (int j=0;j<7;j++){
        int wsI = ng + 4*j;
        win[wsI*64 + o] = qn[j];
    }
    __syncthreads();
    float* qout = q + ((size_t)(b*NN + hs*28))*64;
    #pragma unroll
    for (int j=0;j<7;j++){
        int wsI = ng + 4*j;
        float qa = 0.f;
        for (int oo=0;oo<64;oo++)
            qa = fmaf(win[wsI*64+oo], qw[oo*64+o], qa);
        qout[wsI*64 + o] = qa;
    }
}

// ---------------- Kernel 3: dual attention (two softmaxes, hd=8) ----------------
__global__ __launch_bounds__(256) void kattn(const float* __restrict__ q,
    const float* __restrict__ kvbase,   // k1; v1,k2,v2 at +NQ,+2NQ,+3NQ
    float* __restrict__ z)
{
    __shared__ float kt[4*112*8];   // k1,v1,k2,v2 tiles
    int blk = blockIdx.x;
    int bh = blk >> 2, seg = blk & 3;
    int b = bh >> 3, h = bh & 7;
    int t = threadIdx.x;
    int n = seg*196 + t;
    bool act = t < 196;
    const float scale = 0.35355339059327373f;  // 8^-0.5
    float q8[8];
    #pragma unroll
    for (int j=0;j<8;j++) q8[j] = 0.f;
    if (act){
        const float* qp = q + ((size_t)(b*NN+n))*64 + h*8;
        #pragma unroll
        for (int j=0;j<8;j++) q8[j] = qp[j] * scale;
    }
    float ac1[8], ac2[8]; float d1=0.f, d2=0.f;
    #pragma unroll
    for (int j=0;j<8;j++){ ac1[j]=0.f; ac2[j]=0.f; }

    for (int mt=0; mt<7; mt++){
        __syncthreads();
        for (int li=t; li<896; li+=256){
            int mat = li/224, rem = li%224;
            int mm = rem>>1, half = rem&1;
            const float4* src = (const float4*)(kvbase + (size_t)mat*NQ
                                + ((size_t)(b*NN + mt*112 + mm))*64 + h*8 + half*4);
            ((float4*)kt)[ (mat*112+mm)*2 + half ] = *src;
        }
        __syncthreads();
        if (act){
            for (int mm=0; mm<112; mm++){
                const float* k1p = kt + mm*8;
                const float* v1p = kt + (112+mm)*8;
                const float* k2p = kt + (224+mm)*8;
                const float* v2p = kt + (336+mm)*8;
                float s1=0.f, s2=0.f;
                #pragma unroll
                for (int j=0;j<8;j++){ s1 = fmaf(q8[j],k1p[j],s1); s2 = fmaf(q8[j],k2p[j],s2); }
                float p1 = __expf(s1), p2 = __expf(s2);
                d1 += p1; d2 += p2;
                #pragma unroll
                for (int j=0;j<8;j++){ ac1[j] = fmaf(p1,v1p[j],ac1[j]); ac2[j] = fmaf(p2,v2p[j],ac2[j]); }
            }
        }
    }
    if (act){
        float r1 = 1.f/d1, r2 = 1.f/d2;
        float* zp = z + ((size_t)(b*NN+n))*64 + h*8;
        #pragma unroll
        for (int j=0;j<8;j++) zp[j] = ac1[j]*r1 + ac2[j]*r2;
    }
}

// ---------------- Kernel 4: proj (64->256) + transpose to NCHW ----------------
__global__ __launch_bounds__(256) void kproj(const float* __restrict__ z,
    const float* __restrict__ pw, const float* __restrict__ pb,
    float* __restrict__ zc)
{
    __shared__ float zs[28*64];
    int blk = blockIdx.x;
    int b = blk / 28, hs = blk % 28;
    int t = threadIdx.x;
    const float* zrow = z + ((size_t)(b*NN + hs*28))*64;
    for (int li=t; li<1792; li+=256) zs[li] = zrow[li];
    __syncthreads();
    int c = t;
    float acc[28];
    float bias = pb[c];
    #pragma unroll
    for (int wsI=0; wsI<28; wsI++) acc[wsI] = bias;
    for (int o=0;o<64;o++){
        float wv = pw[o*256 + c];
        #pragma unroll
        for (int wsI=0; wsI<28; wsI++) acc[wsI] = fmaf(zs[wsI*64+o], wv, acc[wsI]);
    }
    float* op = zc + (((size_t)(b*256 + c))*28 + hs)*28;
    #pragma unroll
    for (int f=0; f<7; f++){
        ((float4*)op)[f] = make_float4(acc[4*f], acc[4*f+1], acc[4*f+2], acc[4*f+3]);
    }
}

// ---------------- Kernel 5: bilinear upsample x4 (align_corners=True) ----------------
__global__ __launch_bounds__(256) void kups(const float* __restrict__ zc, float* __restrict__ out)
{
    __shared__ float plane[784];
    __shared__ int   ti0[112];
    __shared__ float twv[112];
    int bc = blockIdx.x;
    int t = threadIdx.x;
    const float* src = zc + (size_t)bc*784;
    for (int li=t; li<784; li+=256) plane[li] = src[li];
    if (t < 112){
        float s = (float)t * (27.f/111.f);
        int i0 = (int)s;
        if (i0 > 27) i0 = 27;
        ti0[t] = i0;
        twv[t] = s - (float)i0;
    }
    __syncthreads();
    float* op = out + (size_t)bc*12544;
    for (int i=t; i<12544; i+=256){
        int y = i/112, xx = i%112;
        int y0 = ti0[y], x0 = ti0[xx];
        float wy = twv[y], wx = twv[xx];
        int y1 = min(y0+1, 27), x1 = min(x0+1, 27);
        const float* r0 = plane + y0*28;
        const float* r1 = plane + y1*28;
        float a  = r0[x0] + (r1[x0]-r0[x0])*wy;
        float bb = r0[x1] + (r1[x1]-r0[x1])*wy;
        op[i] = a + (bb-a)*wx;
    }
}

extern "C" void kernel_launch(void* const* d_in, const int* in_sizes, int n_in,
                              void* d_out, int out_size, void* d_ws, size_t ws_size,
                              hipStream_t stream) {
    const float* x   = (const float*)d_in[0];
    const float* srw = (const float*)d_in[1];
    const float* srb = (const float*)d_in[2];
    const float* lng = (const float*)d_in[3];
    const float* lnb = (const float*)d_in[4];
    const float* qw  = (const float*)d_in[5];
    const float* k1w = (const float*)d_in[6];
    const float* v1w = (const float*)d_in[7];
    const float* k2w = (const float*)d_in[8];
    const float* v2w = (const float*)d_in[9];
    const float* pw  = (const float*)d_in[10];
    const float* pb  = (const float*)d_in[11];

    float* ws = (float*)d_ws;
    float* q  = ws;
    float* k1 = ws + (size_t)1*NQ;
    float* v1 = ws + (size_t)2*NQ;
    float* k2 = ws + (size_t)3*NQ;
    float* v2 = ws + (size_t)4*NQ;
    float* z  = ws + (size_t)5*NQ;
    float* zc = ws + (size_t)6*NQ;   // [B,256,28,28]
    float* out = (float*)d_out;

    kpool<<<16*28*7, 256, 0, stream>>>(x, k1w, v1w, k2w, v2w, k1, v1, k2, v2);
    kconv<<<16*28,   256, 0, stream>>>(x, srw, srb, lng, lnb, qw, q);
    kattn<<<16*8*4,  256, 0, stream>>>(q, k1, z);
    kproj<<<16*28,   256, 0, stream>>>(z, pw, pb, zc);
    kups <<<16*256,  256, 0, stream>>>(zc, out);
}

// Round 3
// 425.577 us; speedup vs baseline: 1.5189x; 1.5189x over previous
//
#include <hip/hip_runtime.h>
#include <math.h>

typedef __attribute__((ext_vector_type(8))) short short8;
typedef __attribute__((ext_vector_type(4))) float f32x4;

#define BB 16
#define NN 784
#define NQ (BB*NN*64)

__device__ __forceinline__ unsigned short f2b(float f){
    unsigned u = __builtin_bit_cast(unsigned, f);
    return (unsigned short)((u + 0x7fffu + ((u>>16)&1u)) >> 16);
}
__device__ __forceinline__ unsigned pk2(float a, float b){
    return (unsigned)f2b(a) | ((unsigned)f2b(b) << 16);
}

#define MFMA16(A,B,C) __builtin_amdgcn_mfma_f32_16x16x32_bf16(A,B,C,0,0,0)

// ============ fused conv(4x4,s4)+bias+LN+qGEMM  AND  max/avg pool + 4 projections ============
// grid: 16 b x 28 hs = 448 blocks, 256 threads (4 waves)
// Swizzle rule: XOR must stay within the row. 256B/128B rows -> (row&7)<<4;
// 64B rows -> (row&3)<<4  (bit6 overflowed the row and collided 7<->8 etc.)
__global__ __launch_bounds__(256) void kcp(
    const float* __restrict__ x, const float* __restrict__ srw,
    const float* __restrict__ srb, const float* __restrict__ lng,
    const float* __restrict__ lnb, const float* __restrict__ qw,
    const float* __restrict__ k1w, const float* __restrict__ v1w,
    const float* __restrict__ k2w, const float* __restrict__ v2w,
    float* __restrict__ q, float* __restrict__ k1, float* __restrict__ v1,
    float* __restrict__ k2, float* __restrict__ v2)
{
    __shared__ __align__(16) char lds[53248];
    char* Abuf = lds;            // [32][128] bf16 swz (rows 28-31 zero); later QN [32][64] bf16 row128B
    char* Bbuf = lds + 8192;     // [64][128] bf16 swz; later D [32][64] f32
    char* QWb  = lds + 24576;    // [64][64] bf16 swz row 128B
    char* PMb  = lds + 32768;    // [32][32] bf16 swz row 64B
    char* PAb  = lds + 34816;    // [32][32] bf16
    char* PWm  = lds + 36864;    // [128][32] bf16 row 64B  (k1w|v1w chunk)
    char* PWa  = lds + 45056;    // [128][32] bf16          (k2w|v2w chunk)

    int blk = blockIdx.x;
    int b = blk / 28, hs = blk % 28;
    int t = threadIdx.x;
    int w = t >> 6, l = t & 63;
    int lr = l & 15, lg = l >> 4;
    int m_p = t % 28, c_p = t / 28;      // pool-pass assignment (t<224)

    // zero pad rows
    ((unsigned*)(Abuf + 7168))[t] = 0;                 // A rows 28..31 (1024B)
    if (t < 64){ ((unsigned*)(PMb + 1792))[t] = 0; ((unsigned*)(PAb + 1792))[t] = 0; }

    // stage qw[o_in][o_out] -> QWb[o_out][k=o_in]
    for (int li = t; li < 4096; li += 256){
        int oi = li >> 6, oo = li & 63;
        *(unsigned short*)(QWb + oo*128 + ((oi*2) ^ ((oo&7)<<4))) = f2b(qw[li]);
    }

    f32x4 ac0={0,0,0,0}, ac1={0,0,0,0};
    f32x4 apm00={0,0,0,0}, apm01={0,0,0,0}, apm10={0,0,0,0}, apm11={0,0,0,0};
    f32x4 apa00={0,0,0,0}, apa01={0,0,0,0}, apa10={0,0,0,0}, apa11={0,0,0,0};

    const float* xb = x + (size_t)b*256*12544 + hs*4*112;

    for (int cc = 0; cc < 32; ++cc){
        __syncthreads();
        { // stage A: 8c x 4r x 28 float4
            const float* xc = xb + (size_t)cc*8*12544;
            for (int li = t; li < 896; li += 256){
                int f = li % 28, cr = li / 28;
                int c = cr >> 2, r = cr & 3;
                float4 v = *(const float4*)(xc + (size_t)c*12544 + r*112 + f*4);
                uint2 u; u.x = pk2(v.x, v.y); u.y = pk2(v.z, v.w);
                *(uint2*)(Abuf + f*256 + (((c*32 + r*8)) ^ ((f&7)<<4))) = u;
            }
        }
        { // stage B: 64o x 32 float4
            const float* wsrc = srw + cc*128;
            #pragma unroll
            for (int i = 0; i < 8; ++i){
                int li = i*256 + t;
                int o = li >> 5, k4 = li & 31;
                float4 v = *(const float4*)(wsrc + o*4096 + k4*4);
                uint2 u; u.x = pk2(v.x, v.y); u.y = pk2(v.z, v.w);
                *(uint2*)(Bbuf + o*256 + ((k4*8) ^ ((o&7)<<4))) = u;
            }
        }
        if ((cc & 3) == 0){ // stage pool weights for this 32-channel group
            int cbase = (cc >> 2) * 32;
            #pragma unroll
            for (int i = 0; i < 16; ++i){
                int li = i*256 + t;
                int half = li >> 11, rem = li & 2047;
                int cl = rem >> 6, o = rem & 63;
                int n = half*64 + o;
                int gi = (cbase + cl)*64 + o;
                float vm = half ? v1w[gi] : k1w[gi];
                float va = half ? v2w[gi] : k2w[gi];
                int byte = (cl*2) ^ ((n&3)<<4);      // 64B row: bits 4-5 only
                *(unsigned short*)(PWm + n*64 + byte) = f2b(vm);
                *(unsigned short*)(PWa + n*64 + byte) = f2b(va);
            }
        }
        __syncthreads();
        // pool pass: per (m,c) reduce the 16 staged values
        if (t < 224){
            int base = m_p*256;
            int byte0 = (c_p*32) ^ ((m_p&7)<<4);
            uint4 A0 = *(const uint4*)(Abuf + base + byte0);
            uint4 A1 = *(const uint4*)(Abuf + base + (byte0 ^ 16));
            unsigned vals[8] = {A0.x,A0.y,A0.z,A0.w,A1.x,A1.y,A1.z,A1.w};
            float mx = -3.4e38f, sm = 0.f;
            #pragma unroll
            for (int i2 = 0; i2 < 8; ++i2){
                float f0 = __builtin_bit_cast(float, vals[i2] << 16);
                float f1 = __builtin_bit_cast(float, vals[i2] & 0xffff0000u);
                mx = fmaxf(mx, fmaxf(f0, f1));
                sm += f0 + f1;
            }
            int cpm = (cc & 3)*8 + c_p;
            int byte = (cpm*2) ^ ((m_p&3)<<4);       // 64B row: bits 4-5 only
            *(unsigned short*)(PMb + m_p*64 + byte) = f2b(mx);
            *(unsigned short*)(PAb + m_p*64 + byte) = f2b(sm * (1.f/16.f));
        }
        // conv MFMAs: wave w owns o-frag w; 2 m-frags x 4 k-steps
        #pragma unroll
        for (int ks = 0; ks < 4; ++ks){
            int kb = ks*64 + lg*16;
            int sw = (lr & 7) << 4;
            short8 bf = *(const short8*)(Bbuf + (w*16+lr)*256 + (kb ^ sw));
            short8 a0 = *(const short8*)(Abuf + lr*256 + (kb ^ sw));
            short8 a1 = *(const short8*)(Abuf + (16+lr)*256 + (kb ^ sw));
            ac0 = MFMA16(a0, bf, ac0);
            ac1 = MFMA16(a1, bf, ac1);
        }
        if ((cc & 3) == 3){ // pool GEMM k-step (K=32)
            __syncthreads();
            int kb = lg*16;
            int sw4 = (lr & 3) << 4;                 // 64B rows
            short8 pm0 = *(const short8*)(PMb + lr*64 + (kb ^ sw4));
            short8 pm1 = *(const short8*)(PMb + (16+lr)*64 + (kb ^ sw4));
            short8 pa0 = *(const short8*)(PAb + lr*64 + (kb ^ sw4));
            short8 pa1 = *(const short8*)(PAb + (16+lr)*64 + (kb ^ sw4));
            int n0 = (w*2)*16 + lr, n1 = (w*2+1)*16 + lr;
            short8 bm0 = *(const short8*)(PWm + n0*64 + (kb ^ sw4));
            short8 bm1 = *(const short8*)(PWm + n1*64 + (kb ^ sw4));
            short8 ba0 = *(const short8*)(PWa + n0*64 + (kb ^ sw4));
            short8 ba1 = *(const short8*)(PWa + n1*64 + (kb ^ sw4));
            apm00 = MFMA16(pm0, bm0, apm00); apm01 = MFMA16(pm0, bm1, apm01);
            apm10 = MFMA16(pm1, bm0, apm10); apm11 = MFMA16(pm1, bm1, apm11);
            apa00 = MFMA16(pa0, ba0, apa00); apa01 = MFMA16(pa0, ba1, apa01);
            apa10 = MFMA16(pa1, ba0, apa10); apa11 = MFMA16(pa1, ba1, apa11);
        }
    }

    __syncthreads();
    // conv D (+bias) -> LDS f32 [32][64]
    float* Db = (float*)Bbuf;
    float bias = srb[w*16 + lr];
    #pragma unroll
    for (int rg = 0; rg < 4; ++rg){
        Db[(lg*4 + rg)*64 + w*16 + lr]      = ac0[rg] + bias;
        Db[(16 + lg*4 + rg)*64 + w*16 + lr] = ac1[rg] + bias;
    }
    __syncthreads();
    // LayerNorm (full-wave reduce over the 64 lanes = 64 channels) -> QN bf16
    unsigned short* QN = (unsigned short*)Abuf;
    float g = lng[l], be = lnb[l];
    #pragma unroll
    for (int i = 0; i < 8; ++i){
        int m = w + i*4;
        float v = Db[m*64 + l];
        float s = v, ss = v*v;
        #pragma unroll
        for (int off = 1; off < 64; off <<= 1){
            s  += __shfl_xor(s,  off, 64);
            ss += __shfl_xor(ss, off, 64);
        }
        float mu = s * (1.f/64.f);
        float var = ss * (1.f/64.f) - mu*mu;
        float qn = (v - mu) * rsqrtf(var + 1e-5f) * g + be;
        *(unsigned short*)((char*)QN + m*128 + ((l*2) ^ ((m&7)<<4))) = f2b(qn);
    }
    __syncthreads();
    // q GEMM: QN[32][64] x QW[64][64]
    f32x4 aq0={0,0,0,0}, aq1={0,0,0,0};
    #pragma unroll
    for (int ks = 0; ks < 2; ++ks){
        int kb = ks*64 + lg*16;
        int sw = (lr & 7) << 4;
        short8 bq = *(const short8*)(QWb + (w*16+lr)*128 + (kb ^ sw));
        short8 a0 = *(const short8*)((char*)QN + lr*128 + (kb ^ sw));
        short8 a1 = *(const short8*)((char*)QN + (16+lr)*128 + (kb ^ sw));
        aq0 = MFMA16(a0, bq, aq0);
        aq1 = MFMA16(a1, bq, aq1);
    }
    // stores
    size_t rowb = (size_t)b*784 + (size_t)hs*28;
    #pragma unroll
    for (int rg = 0; rg < 4; ++rg){
        int m0 = lg*4 + rg, m1 = 16 + lg*4 + rg;
        q[(rowb + m0)*64 + w*16 + lr] = aq0[rg];
        if (m1 < 28) q[(rowb + m1)*64 + w*16 + lr] = aq1[rg];
    }
    int n0 = (w*2)*16 + lr, n1 = (w*2+1)*16 + lr;
    float* dm0 = (n0 < 64) ? k1 : v1; int o0 = n0 & 63;
    float* dm1 = (n1 < 64) ? k1 : v1; int o1 = n1 & 63;
    float* da0 = (n0 < 64) ? k2 : v2;
    float* da1 = (n1 < 64) ? k2 : v2;
    #pragma unroll
    for (int rg = 0; rg < 4; ++rg){
        int m0 = lg*4 + rg, m1 = 16 + lg*4 + rg;
        {
            size_t r0 = (rowb + m0)*64;
            dm0[r0 + o0] = apm00[rg]; dm1[r0 + o1] = apm01[rg];
            da0[r0 + o0] = apa00[rg]; da1[r0 + o1] = apa01[rg];
        }
        if (m1 < 28){
            size_t r1 = (rowb + m1)*64;
            dm0[r1 + o0] = apm10[rg]; dm1[r1 + o1] = apm11[rg];
            da0[r1 + o0] = apa10[rg]; da1[r1 + o1] = apa11[rg];
        }
    }
}

// ---------------- Kernel 3: dual attention (two softmaxes, hd=8) ----------------
__global__ __launch_bounds__(256) void kattn(const float* __restrict__ q,
    const float* __restrict__ kvbase,   // k1; v1,k2,v2 at +NQ,+2NQ,+3NQ
    float* __restrict__ z)
{
    __shared__ float kt[4*112*8];
    int blk = blockIdx.x;
    int bh = blk >> 2, seg = blk & 3;
    int b = bh >> 3, h = bh & 7;
    int t = threadIdx.x;
    int n = seg*196 + t;
    bool act = t < 196;
    const float scale = 0.35355339059327373f;
    float q8[8];
    #pragma unroll
    for (int j=0;j<8;j++) q8[j] = 0.f;
    if (act){
        const float* qp = q + ((size_t)(b*NN+n))*64 + h*8;
        #pragma unroll
        for (int j=0;j<8;j++) q8[j] = qp[j] * scale;
    }
    float ac1[8], ac2[8]; float d1=0.f, d2=0.f;
    #pragma unroll
    for (int j=0;j<8;j++){ ac1[j]=0.f; ac2[j]=0.f; }

    for (int mt=0; mt<7; mt++){
        __syncthreads();
        for (int li=t; li<896; li+=256){
            int mat = li/224, rem = li%224;
            int mm = rem>>1, half = rem&1;
            const float4* src = (const float4*)(kvbase + (size_t)mat*NQ
                                + ((size_t)(b*NN + mt*112 + mm))*64 + h*8 + half*4);
            ((float4*)kt)[ (mat*112+mm)*2 + half ] = *src;
        }
        __syncthreads();
        if (act){
            for (int mm=0; mm<112; mm++){
                const float* k1p = kt + mm*8;
                const float* v1p = kt + (112+mm)*8;
                const float* k2p = kt + (224+mm)*8;
                const float* v2p = kt + (336+mm)*8;
                float s1=0.f, s2=0.f;
                #pragma unroll
                for (int j=0;j<8;j++){ s1 = fmaf(q8[j],k1p[j],s1); s2 = fmaf(q8[j],k2p[j],s2); }
                float p1 = __expf(s1), p2 = __expf(s2);
                d1 += p1; d2 += p2;
                #pragma unroll
                for (int j=0;j<8;j++){ ac1[j] = fmaf(p1,v1p[j],ac1[j]); ac2[j] = fmaf(p2,v2p[j],ac2[j]); }
            }
        }
    }
    if (act){
        float r1 = 1.f/d1, r2 = 1.f/d2;
        float* zp = z + ((size_t)(b*NN+n))*64 + h*8;
        #pragma unroll
        for (int j=0;j<8;j++) zp[j] = ac1[j]*r1 + ac2[j]*r2;
    }
}

// ---------------- Kernel 4: proj (64->256) + transpose to NCHW ----------------
__global__ __launch_bounds__(256) void kproj(const float* __restrict__ z,
    const float* __restrict__ pw, const float* __restrict__ pb,
    float* __restrict__ zc)
{
    __shared__ float zs[28*64];
    int blk = blockIdx.x;
    int b = blk / 28, hs = blk % 28;
    int t = threadIdx.x;
    const float* zrow = z + ((size_t)(b*NN + hs*28))*64;
    for (int li=t; li<1792; li+=256) zs[li] = zrow[li];
    __syncthreads();
    int c = t;
    float acc[28];
    float bias = pb[c];
    #pragma unroll
    for (int wsI=0; wsI<28; wsI++) acc[wsI] = bias;
    for (int o=0;o<64;o++){
        float wv = pw[o*256 + c];
        #pragma unroll
        for (int wsI=0; wsI<28; wsI++) acc[wsI] = fmaf(zs[wsI*64+o], wv, acc[wsI]);
    }
    float* op = zc + (((size_t)(b*256 + c))*28 + hs)*28;
    #pragma unroll
    for (int f=0; f<7; f++){
        ((float4*)op)[f] = make_float4(acc[4*f], acc[4*f+1], acc[4*f+2], acc[4*f+3]);
    }
}

// ---------------- Kernel 5: bilinear upsample x4 (align_corners=True) ----------------
__global__ __launch_bounds__(256) void kups(const float* __restrict__ zc, float* __restrict__ out)
{
    __shared__ float plane[784];
    __shared__ int   ti0[112];
    __shared__ float twv[112];
    int bc = blockIdx.x;
    int t = threadIdx.x;
    const float* src = zc + (size_t)bc*784;
    for (int li=t; li<784; li+=256) plane[li] = src[li];
    if (t < 112){
        float s = (float)t * (27.f/111.f);
        int i0 = (int)s;
        if (i0 > 27) i0 = 27;
        ti0[t] = i0;
        twv[t] = s - (float)i0;
    }
    __syncthreads();
    float* op = out + (size_t)bc*12544;
    for (int i=t; i<12544; i+=256){
        int y = i/112, xx = i%112;
        int y0 = ti0[y], x0 = ti0[xx];
        float wy = twv[y], wx = twv[xx];
        int y1 = min(y0+1, 27), x1 = min(x0+1, 27);
        const float* r0 = plane + y0*28;
        const float* r1 = plane + y1*28;
        float a  = r0[x0] + (r1[x0]-r0[x0])*wy;
        float bb = r0[x1] + (r1[x1]-r0[x1])*wy;
        op[i] = a + (bb-a)*wx;
    }
}

extern "C" void kernel_launch(void* const* d_in, const int* in_sizes, int n_in,
                              void* d_out, int out_size, void* d_ws, size_t ws_size,
                              hipStream_t stream) {
    const float* x   = (const float*)d_in[0];
    const float* srw = (const float*)d_in[1];
    const float* srb = (const float*)d_in[2];
    const float* lng = (const float*)d_in[3];
    const float* lnb = (const float*)d_in[4];
    const float* qw  = (const float*)d_in[5];
    const float* k1w = (const float*)d_in[6];
    const float* v1w = (const float*)d_in[7];
    const float* k2w = (const float*)d_in[8];
    const float* v2w = (const float*)d_in[9];
    const float* pw  = (const float*)d_in[10];
    const float* pb  = (const float*)d_in[11];

    float* ws = (float*)d_ws;
    float* q  = ws;
    float* k1 = ws + (size_t)1*NQ;
    float* v1 = ws + (size_t)2*NQ;
    float* k2 = ws + (size_t)3*NQ;
    float* v2 = ws + (size_t)4*NQ;
    float* z  = ws + (size_t)5*NQ;
    float* zc = ws + (size_t)6*NQ;   // [B,256,28,28]
    float* out = (float*)d_out;

    kcp  <<<16*28,  256, 0, stream>>>(x, srw, srb, lng, lnb, qw, k1w, v1w, k2w, v2w,
                                      q, k1, v1, k2, v2);
    kattn<<<16*8*4, 256, 0, stream>>>(q, k1, z);
    kproj<<<16*28,  256, 0, stream>>>(z, pw, pb, zc);
    kups <<<16*256, 256, 0, stream>>>(zc, out);
}

// Round 4
// 330.395 us; speedup vs baseline: 1.9564x; 1.2881x over previous
//
#include <hip/hip_runtime.h>
#include <math.h>

typedef __attribute__((ext_vector_type(8))) short short8;
typedef __attribute__((ext_vector_type(4))) float f32x4;

#define MFMA16(A,B,C) __builtin_amdgcn_mfma_f32_16x16x32_bf16(A,B,C,0,0,0)

__device__ __forceinline__ unsigned short f2b(float f){
    unsigned u = __builtin_bit_cast(unsigned, f);
    return (unsigned short)((u + 0x7fffu + ((u>>16)&1u)) >> 16);
}
__device__ __forceinline__ unsigned pk2(float a, float b){
    return (unsigned)f2b(a) | ((unsigned)f2b(b) << 16);
}
__device__ __forceinline__ float b2f_lo(unsigned u){ return __builtin_bit_cast(float, u << 16); }
__device__ __forceinline__ float b2f_hi(unsigned u){ return __builtin_bit_cast(float, u & 0xffff0000u); }

// ws layout (bytes):
//  R    @ 0         : 16*784 rows x 1024B  (bf16x512 per row)      12,845,056
//       row: [0..64) q | [64..320) kv packed [h][k1,v1,k2,v2][8] | staging: [0..256) xm, [256..512) xa
//  pws  @ 12845056  : 896 x 1792 f32 conv partials                  6,422,528
//  srwb @ 19267584  : bf16 srw [64][4096]                             524,288
//  Wtm  @ 19791872  : bf16 [128][256]  (k1w|v1w)^T                     65,536
//  Wta  @ 19857408  : bf16 [128][256]  (k2w|v2w)^T                     65,536
//  QWt  @ 19922944  : bf16 [64][64]    qw^T                             8,192
//  z    @ 12845056  : f32 [16*784][64] (aliases pws, dead after k2)  3,211,264
//  zc   @ 16056320  : f32 [16][256][28][28]                          3,211,264

// ---------------- ktw: one-time weight convert/transpose ----------------
__global__ __launch_bounds__(256) void ktw(const float* __restrict__ srw,
    const float* __restrict__ qw, const float* __restrict__ k1w,
    const float* __restrict__ v1w, const float* __restrict__ k2w,
    const float* __restrict__ v2w, char* __restrict__ srwb,
    char* __restrict__ Wtm, char* __restrict__ Wta, char* __restrict__ QWt)
{
    int blk = blockIdx.x, t = threadIdx.x;
    if (blk < 128){
        int base = blk*2048 + t*8;
        float4 a = *(const float4*)(srw + base);
        float4 b = *(const float4*)(srw + base + 4);
        uint4 u = { pk2(a.x,a.y), pk2(a.z,a.w), pk2(b.x,b.y), pk2(b.z,b.w) };
        *(uint4*)(srwb + (size_t)base*2) = u;
    } else if (blk < 136){
        __shared__ float T[256*33];
        int idx = blk - 128, fi = idx >> 1, half = idx & 1;
        const float* src = (fi==0) ? k1w : (fi==1) ? v1w : (fi==2) ? k2w : v2w;
        char* dst = ((fi < 2) ? Wtm : Wta) + (size_t)((fi & 1)*64 + half*32) * 512;
        for (int li = t; li < 8192; li += 256){
            int c = li >> 5, o = li & 31;
            T[c*33 + o] = src[c*64 + half*32 + o];
        }
        __syncthreads();
        for (int lo = t; lo < 1024; lo += 256){
            int o = lo >> 5, c8 = lo & 31;
            float v[8];
            #pragma unroll
            for (int k = 0; k < 8; ++k) v[k] = T[(c8*8 + k)*33 + o];
            uint4 u = { pk2(v[0],v[1]), pk2(v[2],v[3]), pk2(v[4],v[5]), pk2(v[6],v[7]) };
            *(uint4*)(dst + o*512 + c8*16) = u;
        }
    } else {
        __shared__ float T[64*65];
        for (int li = t; li < 4096; li += 256)
            T[(li >> 6)*65 + (li & 63)] = qw[li];
        __syncthreads();
        for (int lo = t; lo < 512; lo += 256){
            int o = lo >> 3, i8 = lo & 7;
            float v[8];
            #pragma unroll
            for (int k = 0; k < 8; ++k) v[k] = T[(i8*8 + k)*65 + o];
            uint4 u = { pk2(v[0],v[1]), pk2(v[2],v[3]), pk2(v[4],v[5]), pk2(v[6],v[7]) };
            *(uint4*)(QWt + o*128 + i8*16) = u;
        }
    }
}

// ---------------- k1: x stream -> pools (xm/xa bf16) + conv partials ----------------
// grid (b,hs,cgp) = 16*28*2 = 896 blocks, 512 threads (8 waves)
__global__ __launch_bounds__(512) void k1(const float* __restrict__ x,
    const char* __restrict__ srwb, char* __restrict__ R, float* __restrict__ pws)
{
    __shared__ __align__(16) char A[32768];     // [32 rows][1024B] bf16 swz
    __shared__ float pm[28*33 + 4];
    __shared__ float pa[28*33 + 4];
    int blk = blockIdx.x;
    int b = blk / 56, r5 = blk % 56, hs = r5 >> 1, cgp = r5 & 1;
    int t = threadIdx.x;
    int w = t >> 6, l = t & 63, lr = l & 15, lg = l >> 4;
    int ofr = w & 3, mfr = w >> 2;
    int c0 = t / 28, p = t % 28;
    f32x4 acc = {0.f,0.f,0.f,0.f};
    const char* Brow = srwb + (size_t)(ofr*16 + lr)*8192 + cgp*4096;
    size_t rowB = (size_t)b*784 + hs*28;

    for (int ci = 0; ci < 4; ++ci){
        int cg = cgp*4 + ci;
        __syncthreads();
        if (t < 448){
            #pragma unroll
            for (int kk = 0; kk < 2; ++kk){
                int c = c0 + kk*16;
                const float* base = x + ((size_t)(b*256 + cg*32 + c)*112 + hs*4)*112 + p*4;
                float4 v0 = *(const float4*)(base);
                float4 v1 = *(const float4*)(base + 112);
                float4 v2 = *(const float4*)(base + 224);
                float4 v3 = *(const float4*)(base + 336);
                float mx = fmaxf(fmaxf(fmaxf(v0.x,v0.y),fmaxf(v0.z,v0.w)),
                                 fmaxf(fmaxf(v1.x,v1.y),fmaxf(v1.z,v1.w)));
                mx = fmaxf(mx, fmaxf(fmaxf(fmaxf(v2.x,v2.y),fmaxf(v2.z,v2.w)),
                                     fmaxf(fmaxf(v3.x,v3.y),fmaxf(v3.z,v3.w))));
                float sm = (v0.x+v0.y+v0.z+v0.w)+(v1.x+v1.y+v1.z+v1.w)
                         + (v2.x+v2.y+v2.z+v2.w)+(v3.x+v3.y+v3.z+v3.w);
                pm[p*33 + c] = mx;
                pa[p*33 + c] = sm * (1.f/16.f);
                char* Ap = A + p*1024;
                int swz = (p & 7) << 4;
                uint2 u0 = { pk2(v0.x,v0.y), pk2(v0.z,v0.w) };
                uint2 u1 = { pk2(v1.x,v1.y), pk2(v1.z,v1.w) };
                uint2 u2 = { pk2(v2.x,v2.y), pk2(v2.z,v2.w) };
                uint2 u3 = { pk2(v3.x,v3.y), pk2(v3.z,v3.w) };
                *(uint2*)(Ap + ((c*32 +  0) ^ swz)) = u0;
                *(uint2*)(Ap + ((c*32 +  8) ^ swz)) = u1;
                *(uint2*)(Ap + ((c*32 + 16) ^ swz)) = u2;
                *(uint2*)(Ap + ((c*32 + 24) ^ swz)) = u3;
            }
        }
        __syncthreads();
        if (t < 112){   // pool -> global (32-ch stripe per chunk)
            int m = t >> 2, c8 = t & 3;
            float vm[8], va8[8];
            #pragma unroll
            for (int k = 0; k < 8; ++k){
                vm[k]  = pm[m*33 + c8*8 + k];
                va8[k] = pa[m*33 + c8*8 + k];
            }
            uint4 um = { pk2(vm[0],vm[1]), pk2(vm[2],vm[3]), pk2(vm[4],vm[5]), pk2(vm[6],vm[7]) };
            uint4 ua = { pk2(va8[0],va8[1]), pk2(va8[2],va8[3]), pk2(va8[4],va8[5]), pk2(va8[6],va8[7]) };
            *(uint4*)(R + (rowB + m)*1024 + cg*64 + c8*16)       = um;
            *(uint4*)(R + (rowB + m)*1024 + 512 + cg*64 + c8*16) = ua;
        }
        const char* Arow = A + (mfr*16 + lr)*1024;
        const char* Bc = Brow + ci*1024;
        int swzr = (lr & 7) << 4;
        #pragma unroll
        for (int ks = 0; ks < 16; ++ks){
            int kb = ks*64 + lg*16;
            short8 a  = *(const short8*)(Arow + (kb ^ swzr));
            short8 bf = *(const short8*)(Bc + kb);
            acc = MFMA16(a, bf, acc);
        }
    }
    float* pp = pws + (size_t)((b*28 + hs)*2 + cgp)*1792;
    #pragma unroll
    for (int rg = 0; rg < 4; ++rg){
        int m = mfr*16 + lg*4 + rg;
        if (m < 28) pp[m*64 + ofr*16 + lr] = acc[rg];
    }
}

// ---------------- k2: partial-sum + LN + qGEMM + pool GEMMs ----------------
// grid (b,hs) = 448 blocks, 512 threads
__global__ __launch_bounds__(512) void k2(const float* __restrict__ pws_,
    const float* __restrict__ srb, const float* __restrict__ lng,
    const float* __restrict__ lnb, const char* __restrict__ Wtm,
    const char* __restrict__ Wta, const char* __restrict__ QWt,
    char* __restrict__ R)
{
    __shared__ __align__(16) char PM[16384];    // [32][512B] bf16 swz
    __shared__ __align__(16) char PA[16384];
    __shared__ float Db[32*64];
    __shared__ __align__(16) char QN[4096];     // [32][128B] bf16 swz
    int blk = blockIdx.x, b = blk/28, hs = blk%28;
    int t = threadIdx.x, w = t>>6, l = t&63, lr = l&15, lg = l>>4;
    size_t rowB = (size_t)b*784 + hs*28;
    const char* Rb = R + rowB*1024;
    for (int li = t; li < 896; li += 512){
        int m = li >> 5, c16 = li & 31;
        uint4 vm = *(const uint4*)(Rb + (size_t)m*1024 + c16*16);
        uint4 va = *(const uint4*)(Rb + (size_t)m*1024 + 512 + c16*16);
        int dst = m*512 + ((c16*16) ^ ((m&7)<<4));
        *(uint4*)(PM + dst) = vm;
        *(uint4*)(PA + dst) = va;
    }
    const float* p0 = pws_ + (size_t)(b*28 + hs)*2*1792;
    const float* p1 = p0 + 1792;
    for (int e = t; e < 1792; e += 512)
        Db[e] = p0[e] + p1[e] + srb[e & 63];
    __syncthreads();
    float g = lng[l], be = lnb[l];
    #pragma unroll
    for (int i = 0; i < 4; ++i){
        int m = w + i*8;
        float v = Db[m*64 + l];
        float s = v, ss = v*v;
        #pragma unroll
        for (int off = 1; off < 64; off <<= 1){
            s  += __shfl_xor(s,  off, 64);
            ss += __shfl_xor(ss, off, 64);
        }
        float mu = s * (1.f/64.f);
        float var = ss * (1.f/64.f) - mu*mu;
        float qn = (v - mu) * rsqrtf(var + 1e-5f) * g + be;
        *(unsigned short*)(QN + m*128 + ((l*2) ^ ((m&7)<<4))) = f2b(qn);
    }
    __syncthreads();
    int fam = w >> 2, ofp = w & 3;
    const char* PMA = fam ? PA : PM;
    const char* Wt  = fam ? Wta : Wtm;
    f32x4 a00={0.f,0.f,0.f,0.f}, a01=a00, a10=a00, a11=a00;
    int swzr = (lr & 7) << 4;
    #pragma unroll
    for (int ks = 0; ks < 8; ++ks){
        int kb = ks*64 + lg*16;
        short8 x0 = *(const short8*)(PMA + lr*512 + (kb ^ swzr));
        short8 x1 = *(const short8*)(PMA + (16+lr)*512 + (kb ^ swzr));
        short8 b0 = *(const short8*)(Wt + (size_t)(ofp*32 + lr)*512 + kb);
        short8 b1 = *(const short8*)(Wt + (size_t)(ofp*32 + 16 + lr)*512 + kb);
        a00 = MFMA16(x0, b0, a00); a01 = MFMA16(x0, b1, a01);
        a10 = MFMA16(x1, b0, a10); a11 = MFMA16(x1, b1, a11);
    }
    f32x4 q0={0.f,0.f,0.f,0.f}, q1=q0;
    if (w < 4){
        #pragma unroll
        for (int ks = 0; ks < 2; ++ks){
            int kb = ks*64 + lg*16;
            short8 xa_ = *(const short8*)(QN + lr*128 + (kb ^ swzr));
            short8 xb_ = *(const short8*)(QN + (16+lr)*128 + (kb ^ swzr));
            short8 bq  = *(const short8*)(QWt + (size_t)(w*16 + lr)*128 + kb);
            q0 = MFMA16(xa_, bq, q0);
            q1 = MFMA16(xb_, bq, q1);
        }
    }
    #pragma unroll
    for (int j = 0; j < 2; ++j){
        int o128 = ofp*32 + j*16 + lr;
        int o = o128 & 63, hh = o >> 3, dd = o & 7, mat = fam*2 + (o128 >> 6);
        int byteoff = 128 + hh*64 + mat*16 + dd*2;
        f32x4 am  = j ? a01 : a00;
        f32x4 am1 = j ? a11 : a10;
        #pragma unroll
        for (int rg = 0; rg < 4; ++rg){
            int m0 = lg*4 + rg, m1 = 16 + lg*4 + rg;
            *(unsigned short*)(R + (rowB + m0)*1024 + byteoff) = f2b(am[rg]);
            if (m1 < 28)
                *(unsigned short*)(R + (rowB + m1)*1024 + byteoff) = f2b(am1[rg]);
        }
    }
    if (w < 4){
        int o = w*16 + lr;
        #pragma unroll
        for (int rg = 0; rg < 4; ++rg){
            int m0 = lg*4 + rg, m1 = 16 + lg*4 + rg;
            *(unsigned short*)(R + (rowB + m0)*1024 + o*2) = f2b(q0[rg]);
            if (m1 < 28)
                *(unsigned short*)(R + (rowB + m1)*1024 + o*2) = f2b(q1[rg]);
        }
    }
}

// ---------------- kattn: dual attention (bf16 q/kv in R) ----------------
__global__ __launch_bounds__(256) void kattn(const char* __restrict__ R, float* __restrict__ z)
{
    __shared__ float kt[4*112*8];
    int blk = blockIdx.x, bh = blk >> 2, seg = blk & 3;
    int b = bh >> 3, h = bh & 7;
    int t = threadIdx.x, n = seg*196 + t;
    bool act = t < 196;
    const float scale = 0.35355339059327373f;
    float q8[8];
    #pragma unroll
    for (int j = 0; j < 8; ++j) q8[j] = 0.f;
    if (act){
        uint4 qv = *(const uint4*)(R + ((size_t)b*784 + n)*1024 + h*16);
        q8[0] = b2f_lo(qv.x)*scale; q8[1] = b2f_hi(qv.x)*scale;
        q8[2] = b2f_lo(qv.y)*scale; q8[3] = b2f_hi(qv.y)*scale;
        q8[4] = b2f_lo(qv.z)*scale; q8[5] = b2f_hi(qv.z)*scale;
        q8[6] = b2f_lo(qv.w)*scale; q8[7] = b2f_hi(qv.w)*scale;
    }
    float ac1[8], ac2[8]; float d1 = 0.f, d2 = 0.f;
    #pragma unroll
    for (int j = 0; j < 8; ++j){ ac1[j] = 0.f; ac2[j] = 0.f; }

    for (int mt = 0; mt < 7; ++mt){
        __syncthreads();
        for (int li = t; li < 448; li += 256){
            int mm = li >> 2, part = li & 3;
            uint4 v = *(const uint4*)(R + ((size_t)b*784 + mt*112 + mm)*1024 + 128 + h*64 + part*16);
            float* kp = kt + (part*112 + mm)*8;
            float4 A = { b2f_lo(v.x), b2f_hi(v.x), b2f_lo(v.y), b2f_hi(v.y) };
            float4 Bv = { b2f_lo(v.z), b2f_hi(v.z), b2f_lo(v.w), b2f_hi(v.w) };
            *(float4*)(kp) = A;
            *(float4*)(kp + 4) = Bv;
        }
        __syncthreads();
        if (act){
            for (int mm = 0; mm < 112; ++mm){
                const float* k1p = kt + mm*8;
                const float* v1p = kt + (112+mm)*8;
                const float* k2p = kt + (224+mm)*8;
                const float* v2p = kt + (336+mm)*8;
                float s1 = 0.f, s2 = 0.f;
                #pragma unroll
                for (int j = 0; j < 8; ++j){ s1 = fmaf(q8[j],k1p[j],s1); s2 = fmaf(q8[j],k2p[j],s2); }
                float p1 = __expf(s1), p2 = __expf(s2);
                d1 += p1; d2 += p2;
                #pragma unroll
                for (int j = 0; j < 8; ++j){ ac1[j] = fmaf(p1,v1p[j],ac1[j]); ac2[j] = fmaf(p2,v2p[j],ac2[j]); }
            }
        }
    }
    if (act){
        float r1 = 1.f/d1, r2 = 1.f/d2;
        float* zp = z + ((size_t)b*784 + n)*64 + h*8;
        #pragma unroll
        for (int j = 0; j < 8; ++j) zp[j] = ac1[j]*r1 + ac2[j]*r2;
    }
}

// ---------------- kproj ----------------
__global__ __launch_bounds__(256) void kproj(const float* __restrict__ z,
    const float* __restrict__ pw, const float* __restrict__ pb,
    float* __restrict__ zc)
{
    __shared__ float zs[28*64];
    int blk = blockIdx.x;
    int b = blk / 28, hs = blk % 28;
    int t = threadIdx.x;
    const float* zrow = z + ((size_t)b*784 + hs*28)*64;
    for (int li = t; li < 1792; li += 256) zs[li] = zrow[li];
    __syncthreads();
    int c = t;
    float acc[28];
    float bias = pb[c];
    #pragma unroll
    for (int wsI = 0; wsI < 28; ++wsI) acc[wsI] = bias;
    for (int o = 0; o < 64; ++o){
        float wv = pw[o*256 + c];
        #pragma unroll
        for (int wsI = 0; wsI < 28; ++wsI) acc[wsI] = fmaf(zs[wsI*64+o], wv, acc[wsI]);
    }
    float* op = zc + (((size_t)(b*256 + c))*28 + hs)*28;
    #pragma unroll
    for (int f = 0; f < 7; ++f)
        ((float4*)op)[f] = make_float4(acc[4*f], acc[4*f+1], acc[4*f+2], acc[4*f+3]);
}

// ---------------- kups ----------------
__global__ __launch_bounds__(256) void kups(const float* __restrict__ zc, float* __restrict__ out)
{
    __shared__ float plane[784];
    __shared__ int   ti0[112];
    __shared__ float twv[112];
    int bc = blockIdx.x;
    int t = threadIdx.x;
    const float* src = zc + (size_t)bc*784;
    for (int li = t; li < 784; li += 256) plane[li] = src[li];
    if (t < 112){
        float s = (float)t * (27.f/111.f);
        int i0 = (int)s;
        if (i0 > 27) i0 = 27;
        ti0[t] = i0;
        twv[t] = s - (float)i0;
    }
    __syncthreads();
    float* op = out + (size_t)bc*12544;
    for (int i = t; i < 12544; i += 256){
        int y = i/112, xx = i%112;
        int y0 = ti0[y], x0 = ti0[xx];
        float wy = twv[y], wx = twv[xx];
        int y1 = min(y0+1, 27), x1 = min(x0+1, 27);
        const float* r0 = plane + y0*28;
        const float* r1 = plane + y1*28;
        float a  = r0[x0] + (r1[x0]-r0[x0])*wy;
        float bb = r0[x1] + (r1[x1]-r0[x1])*wy;
        op[i] = a + (bb-a)*wx;
    }
}

extern "C" void kernel_launch(void* const* d_in, const int* in_sizes, int n_in,
                              void* d_out, int out_size, void* d_ws, size_t ws_size,
                              hipStream_t stream) {
    const float* x   = (const float*)d_in[0];
    const float* srw = (const float*)d_in[1];
    const float* srb = (const float*)d_in[2];
    const float* lng = (const float*)d_in[3];
    const float* lnb = (const float*)d_in[4];
    const float* qw  = (const float*)d_in[5];
    const float* k1w = (const float*)d_in[6];
    const float* v1w = (const float*)d_in[7];
    const float* k2w = (const float*)d_in[8];
    const float* v2w = (const float*)d_in[9];
    const float* pw  = (const float*)d_in[10];
    const float* pb  = (const float*)d_in[11];

    char*  Rws  = (char*)d_ws;
    float* pws  = (float*)(Rws + 12845056);
    char*  srwb = Rws + 19267584;
    char*  Wtm  = Rws + 19791872;
    char*  Wta  = Rws + 19857408;
    char*  QWt  = Rws + 19922944;
    float* z    = (float*)(Rws + 12845056);   // aliases pws (dead after k2)
    float* zc   = z + 802816;
    float* out  = (float*)d_out;

    ktw  <<<137, 256, 0, stream>>>(srw, qw, k1w, v1w, k2w, v2w, srwb, Wtm, Wta, QWt);
    k1   <<<896, 512, 0, stream>>>(x, srwb, Rws, pws);
    k2   <<<448, 512, 0, stream>>>(pws, srb, lng, lnb, Wtm, Wta, QWt, Rws);
    kattn<<<512, 256, 0, stream>>>(Rws, z);
    kproj<<<448, 256, 0, stream>>>(z, pw, pb, zc);
    kups <<<4096, 256, 0, stream>>>(zc, out);
}

// Round 5
// 270.401 us; speedup vs baseline: 2.3905x; 1.2219x over previous
//
#include <hip/hip_runtime.h>
#include <math.h>

typedef __attribute__((ext_vector_type(8))) short short8;
typedef __attribute__((ext_vector_type(4))) short bh4;
typedef __attribute__((ext_vector_type(4))) float f32x4;
typedef __attribute__((ext_vector_type(2))) unsigned uint2v;

#define MFMA16(A,B,C) __builtin_amdgcn_mfma_f32_16x16x32_bf16(A,B,C,0,0,0)

#if __has_builtin(__builtin_amdgcn_mfma_f32_16x16x16bf16_1k)
#define MFMA16x16(A,B,C) __builtin_amdgcn_mfma_f32_16x16x16bf16_1k(A,B,C,0,0,0)
#else
__device__ __forceinline__ f32x4 mfma16x16_asm(bh4 a, bh4 b, f32x4 c){
    asm volatile("v_mfma_f32_16x16x16_bf16 %0, %1, %2, %0" : "+v"(c) : "v"(a), "v"(b));
    return c;
}
#define MFMA16x16(A,B,C) mfma16x16_asm(A,B,C)
#endif

__device__ __forceinline__ unsigned short f2b(float f){
    unsigned u = __builtin_bit_cast(unsigned, f);
    return (unsigned short)((u + 0x7fffu + ((u>>16)&1u)) >> 16);
}
__device__ __forceinline__ unsigned pk2(float a, float b){
    return (unsigned)f2b(a) | ((unsigned)f2b(b) << 16);
}
// round-half-up pack (cheap, 0.5ulp like RNE)
__device__ __forceinline__ unsigned pk2rn(float a, float b){
    unsigned ua = __builtin_bit_cast(unsigned, a) + 0x8000u;
    unsigned ub = __builtin_bit_cast(unsigned, b) + 0x8000u;
    return (ua >> 16) | (ub & 0xffff0000u);
}
__device__ __forceinline__ float b2f_lo(unsigned u){ return __builtin_bit_cast(float, u << 16); }
__device__ __forceinline__ float b2f_hi(unsigned u){ return __builtin_bit_cast(float, u & 0xffff0000u); }

// ws layout: see round-3 comment (unchanged)

// ---------------- ktw: one-time weight convert/transpose ----------------
__global__ __launch_bounds__(256) void ktw(const float* __restrict__ srw,
    const float* __restrict__ qw, const float* __restrict__ k1w,
    const float* __restrict__ v1w, const float* __restrict__ k2w,
    const float* __restrict__ v2w, char* __restrict__ srwb,
    char* __restrict__ Wtm, char* __restrict__ Wta, char* __restrict__ QWt)
{
    int blk = blockIdx.x, t = threadIdx.x;
    if (blk < 128){
        int base = blk*2048 + t*8;
        float4 a = *(const float4*)(srw + base);
        float4 b = *(const float4*)(srw + base + 4);
        uint4 u = { pk2(a.x,a.y), pk2(a.z,a.w), pk2(b.x,b.y), pk2(b.z,b.w) };
        *(uint4*)(srwb + (size_t)base*2) = u;
    } else if (blk < 136){
        __shared__ float T[256*33];
        int idx = blk - 128, fi = idx >> 1, half = idx & 1;
        const float* src = (fi==0) ? k1w : (fi==1) ? v1w : (fi==2) ? k2w : v2w;
        char* dst = ((fi < 2) ? Wtm : Wta) + (size_t)((fi & 1)*64 + half*32) * 512;
        for (int li = t; li < 8192; li += 256){
            int c = li >> 5, o = li & 31;
            T[c*33 + o] = src[c*64 + half*32 + o];
        }
        __syncthreads();
        for (int lo = t; lo < 1024; lo += 256){
            int o = lo >> 5, c8 = lo & 31;
            float v[8];
            #pragma unroll
            for (int k = 0; k < 8; ++k) v[k] = T[(c8*8 + k)*33 + o];
            uint4 u = { pk2(v[0],v[1]), pk2(v[2],v[3]), pk2(v[4],v[5]), pk2(v[6],v[7]) };
            *(uint4*)(dst + o*512 + c8*16) = u;
        }
    } else {
        __shared__ float T[64*65];
        for (int li = t; li < 4096; li += 256)
            T[(li >> 6)*65 + (li & 63)] = qw[li];
        __syncthreads();
        for (int lo = t; lo < 512; lo += 256){
            int o = lo >> 3, i8 = lo & 7;
            float v[8];
            #pragma unroll
            for (int k = 0; k < 8; ++k) v[k] = T[(i8*8 + k)*65 + o];
            uint4 u = { pk2(v[0],v[1]), pk2(v[2],v[3]), pk2(v[4],v[5]), pk2(v[6],v[7]) };
            *(uint4*)(QWt + o*128 + i8*16) = u;
        }
    }
}

// ---------------- k1: x stream -> pools (xm/xa bf16) + conv partials ----------------
__global__ __launch_bounds__(512) void k1(const float* __restrict__ x,
    const char* __restrict__ srwb, char* __restrict__ R, float* __restrict__ pws)
{
    __shared__ __align__(16) char A[32768];
    __shared__ float pm[28*33 + 4];
    __shared__ float pa[28*33 + 4];
    int blk = blockIdx.x;
    int b = blk / 56, r5 = blk % 56, hs = r5 >> 1, cgp = r5 & 1;
    int t = threadIdx.x;
    int w = t >> 6, l = t & 63, lr = l & 15, lg = l >> 4;
    int ofr = w & 3, mfr = w >> 2;
    int c0 = t / 28, p = t % 28;
    f32x4 acc = {0.f,0.f,0.f,0.f};
    const char* Brow = srwb + (size_t)(ofr*16 + lr)*8192 + cgp*4096;
    size_t rowB = (size_t)b*784 + hs*28;

    for (int ci = 0; ci < 4; ++ci){
        int cg = cgp*4 + ci;
        __syncthreads();
        if (t < 448){
            #pragma unroll
            for (int kk = 0; kk < 2; ++kk){
                int c = c0 + kk*16;
                const float* base = x + ((size_t)(b*256 + cg*32 + c)*112 + hs*4)*112 + p*4;
                float4 v0 = *(const float4*)(base);
                float4 v1 = *(const float4*)(base + 112);
                float4 v2 = *(const float4*)(base + 224);
                float4 v3 = *(const float4*)(base + 336);
                float mx = fmaxf(fmaxf(fmaxf(v0.x,v0.y),fmaxf(v0.z,v0.w)),
                                 fmaxf(fmaxf(v1.x,v1.y),fmaxf(v1.z,v1.w)));
                mx = fmaxf(mx, fmaxf(fmaxf(fmaxf(v2.x,v2.y),fmaxf(v2.z,v2.w)),
                                     fmaxf(fmaxf(v3.x,v3.y),fmaxf(v3.z,v3.w))));
                float sm = (v0.x+v0.y+v0.z+v0.w)+(v1.x+v1.y+v1.z+v1.w)
                         + (v2.x+v2.y+v2.z+v2.w)+(v3.x+v3.y+v3.z+v3.w);
                pm[p*33 + c] = mx;
                pa[p*33 + c] = sm * (1.f/16.f);
                char* Ap = A + p*1024;
                int swz = (p & 7) << 4;
                uint2 u0 = { pk2(v0.x,v0.y), pk2(v0.z,v0.w) };
                uint2 u1 = { pk2(v1.x,v1.y), pk2(v1.z,v1.w) };
                uint2 u2 = { pk2(v2.x,v2.y), pk2(v2.z,v2.w) };
                uint2 u3 = { pk2(v3.x,v3.y), pk2(v3.z,v3.w) };
                *(uint2*)(Ap + ((c*32 +  0) ^ swz)) = u0;
                *(uint2*)(Ap + ((c*32 +  8) ^ swz)) = u1;
                *(uint2*)(Ap + ((c*32 + 16) ^ swz)) = u2;
                *(uint2*)(Ap + ((c*32 + 24) ^ swz)) = u3;
            }
        }
        __syncthreads();
        if (t < 112){
            int m = t >> 2, c8 = t & 3;
            float vm[8], va8[8];
            #pragma unroll
            for (int k = 0; k < 8; ++k){
                vm[k]  = pm[m*33 + c8*8 + k];
                va8[k] = pa[m*33 + c8*8 + k];
            }
            uint4 um = { pk2(vm[0],vm[1]), pk2(vm[2],vm[3]), pk2(vm[4],vm[5]), pk2(vm[6],vm[7]) };
            uint4 ua = { pk2(va8[0],va8[1]), pk2(va8[2],va8[3]), pk2(va8[4],va8[5]), pk2(va8[6],va8[7]) };
            *(uint4*)(R + (rowB + m)*1024 + cg*64 + c8*16)       = um;
            *(uint4*)(R + (rowB + m)*1024 + 512 + cg*64 + c8*16) = ua;
        }
        const char* Arow = A + (mfr*16 + lr)*1024;
        const char* Bc = Brow + ci*1024;
        int swzr = (lr & 7) << 4;
        #pragma unroll
        for (int ks = 0; ks < 16; ++ks){
            int kb = ks*64 + lg*16;
            short8 a  = *(const short8*)(Arow + (kb ^ swzr));
            short8 bf = *(const short8*)(Bc + kb);
            acc = MFMA16(a, bf, acc);
        }
    }
    float* pp = pws + (size_t)((b*28 + hs)*2 + cgp)*1792;
    #pragma unroll
    for (int rg = 0; rg < 4; ++rg){
        int m = mfr*16 + lg*4 + rg;
        if (m < 28) pp[m*64 + ofr*16 + lr] = acc[rg];
    }
}

// ---------------- k2: partial-sum + LN + qGEMM + pool GEMMs ----------------
__global__ __launch_bounds__(512) void k2(const float* __restrict__ pws_,
    const float* __restrict__ srb, const float* __restrict__ lng,
    const float* __restrict__ lnb, const char* __restrict__ Wtm,
    const char* __restrict__ Wta, const char* __restrict__ QWt,
    char* __restrict__ R)
{
    __shared__ __align__(16) char PM[16384];
    __shared__ __align__(16) char PA[16384];
    __shared__ float Db[32*64];
    __shared__ __align__(16) char QN[4096];
    int blk = blockIdx.x, b = blk/28, hs = blk%28;
    int t = threadIdx.x, w = t>>6, l = t&63, lr = l&15, lg = l>>4;
    size_t rowB = (size_t)b*784 + hs*28;
    const char* Rb = R + rowB*1024;
    for (int li = t; li < 896; li += 512){
        int m = li >> 5, c16 = li & 31;
        uint4 vm = *(const uint4*)(Rb + (size_t)m*1024 + c16*16);
        uint4 va = *(const uint4*)(Rb + (size_t)m*1024 + 512 + c16*16);
        int dst = m*512 + ((c16*16) ^ ((m&7)<<4));
        *(uint4*)(PM + dst) = vm;
        *(uint4*)(PA + dst) = va;
    }
    const float* p0 = pws_ + (size_t)(b*28 + hs)*2*1792;
    const float* p1 = p0 + 1792;
    for (int e = t; e < 1792; e += 512)
        Db[e] = p0[e] + p1[e] + srb[e & 63];
    __syncthreads();
    float g = lng[l], be = lnb[l];
    #pragma unroll
    for (int i = 0; i < 4; ++i){
        int m = w + i*8;
        float v = Db[m*64 + l];
        float s = v, ss = v*v;
        #pragma unroll
        for (int off = 1; off < 64; off <<= 1){
            s  += __shfl_xor(s,  off, 64);
            ss += __shfl_xor(ss, off, 64);
        }
        float mu = s * (1.f/64.f);
        float var = ss * (1.f/64.f) - mu*mu;
        float qn = (v - mu) * rsqrtf(var + 1e-5f) * g + be;
        *(unsigned short*)(QN + m*128 + ((l*2) ^ ((m&7)<<4))) = f2b(qn);
    }
    __syncthreads();
    int fam = w >> 2, ofp = w & 3;
    const char* PMA = fam ? PA : PM;
    const char* Wt  = fam ? Wta : Wtm;
    f32x4 a00={0.f,0.f,0.f,0.f}, a01=a00, a10=a00, a11=a00;
    int swzr = (lr & 7) << 4;
    #pragma unroll
    for (int ks = 0; ks < 8; ++ks){
        int kb = ks*64 + lg*16;
        short8 x0 = *(const short8*)(PMA + lr*512 + (kb ^ swzr));
        short8 x1 = *(const short8*)(PMA + (16+lr)*512 + (kb ^ swzr));
        short8 b0 = *(const short8*)(Wt + (size_t)(ofp*32 + lr)*512 + kb);
        short8 b1 = *(const short8*)(Wt + (size_t)(ofp*32 + 16 + lr)*512 + kb);
        a00 = MFMA16(x0, b0, a00); a01 = MFMA16(x0, b1, a01);
        a10 = MFMA16(x1, b0, a10); a11 = MFMA16(x1, b1, a11);
    }
    f32x4 q0={0.f,0.f,0.f,0.f}, q1=q0;
    if (w < 4){
        #pragma unroll
        for (int ks = 0; ks < 2; ++ks){
            int kb = ks*64 + lg*16;
            short8 xa_ = *(const short8*)(QN + lr*128 + (kb ^ swzr));
            short8 xb_ = *(const short8*)(QN + (16+lr)*128 + (kb ^ swzr));
            short8 bq  = *(const short8*)(QWt + (size_t)(w*16 + lr)*128 + kb);
            q0 = MFMA16(xa_, bq, q0);
            q1 = MFMA16(xb_, bq, q1);
        }
    }
    #pragma unroll
    for (int j = 0; j < 2; ++j){
        int o128 = ofp*32 + j*16 + lr;
        int o = o128 & 63, hh = o >> 3, dd = o & 7, mat = fam*2 + (o128 >> 6);
        int byteoff = 128 + hh*64 + mat*16 + dd*2;
        f32x4 am  = j ? a01 : a00;
        f32x4 am1 = j ? a11 : a10;
        #pragma unroll
        for (int rg = 0; rg < 4; ++rg){
            int m0 = lg*4 + rg, m1 = 16 + lg*4 + rg;
            *(unsigned short*)(R + (rowB + m0)*1024 + byteoff) = f2b(am[rg]);
            if (m1 < 28)
                *(unsigned short*)(R + (rowB + m1)*1024 + byteoff) = f2b(am1[rg]);
        }
    }
    if (w < 4){
        int o = w*16 + lr;
        #pragma unroll
        for (int rg = 0; rg < 4; ++rg){
            int m0 = lg*4 + rg, m1 = 16 + lg*4 + rg;
            *(unsigned short*)(R + (rowB + m0)*1024 + o*2) = f2b(q0[rg]);
            if (m1 < 28)
                *(unsigned short*)(R + (rowB + m1)*1024 + o*2) = f2b(q1[rg]);
        }
    }
}

// ---------------- kattn: MFMA dual attention (swapped-operand, hd=8 pad 16) ----------------
// grid: (b,h) x 7 n-segments = 896 blocks, 256 threads (4 waves); wave owns 28 n-rows.
__global__ __launch_bounds__(256) void kattn(const char* __restrict__ R, float* __restrict__ z)
{
    __shared__ __align__(16) char QT [6144];   // [128][48B]  rows: 16 bf16 (k pad 8..15 = 0)
    __shared__ __align__(16) char K1b[5376];   // [112][48B]
    __shared__ __align__(16) char K2b[5376];
    __shared__ __align__(16) char VT1[3840];   // [16][240B]  rows d (pad 8..15 = 0)
    __shared__ __align__(16) char VT2[3840];
    int blk = blockIdx.x;
    int bh = blk / 7, nseg = blk % 7;
    int b = bh >> 3, h = bh & 7;
    int t = threadIdx.x, w = t >> 6, l = t & 63;
    int col = l & 15, g = l >> 4;

    // zero-init pads (QT fully; K k-pad; VT rows 8..15)
    for (int i = t; i < 384; i += 256) ((uint4*)QT)[i] = uint4{0,0,0,0};
    for (int i = t; i < 112; i += 256){
        *(uint4*)(K1b + i*48 + 16) = uint4{0,0,0,0};
        *(uint4*)(K2b + i*48 + 16) = uint4{0,0,0,0};
    }
    for (int i = t; i < 120; i += 256){
        *(uint4*)(VT1 + 1920 + i*16) = uint4{0,0,0,0};
        *(uint4*)(VT2 + 1920 + i*16) = uint4{0,0,0,0};
    }
    __syncthreads();
    if (t < 112){
        uint4 qv = *(const uint4*)(R + ((size_t)b*784 + nseg*112 + t)*1024 + h*16);
        *(uint2*)(QT + t*48)     = uint2{qv.x, qv.y};
        *(uint2*)(QT + t*48 + 8) = uint2{qv.z, qv.w};
    }
    __syncthreads();

    bh4 qf[2];
    #pragma unroll
    for (int nf = 0; nf < 2; ++nf)
        qf[nf] = *(const bh4*)(QT + (w*28 + nf*16 + col)*48 + g*8);

    f32x4 o1[2] = {{0,0,0,0},{0,0,0,0}}, o2[2] = {{0,0,0,0},{0,0,0,0}};
    float d1[2] = {0.f,0.f}, d2[2] = {0.f,0.f};
    const float C2 = 0.51004244f;   // 8^-0.5 * log2(e)

    for (int mt = 0; mt < 7; ++mt){
        __syncthreads();
        for (int li = t; li < 448; li += 256){
            int m = li >> 2, part = li & 3;
            uint4 v = *(const uint4*)(R + ((size_t)b*784 + mt*112 + m)*1024 + 128 + h*64 + part*16);
            if ((part & 1) == 0){
                char* Kb = (part == 0) ? K1b : K2b;
                *(uint2*)(Kb + m*48)     = uint2{v.x, v.y};
                *(uint2*)(Kb + m*48 + 8) = uint2{v.z, v.w};
            } else {
                char* Vb = (part == 1) ? VT1 : VT2;
                unsigned arr[4] = {v.x, v.y, v.z, v.w};
                #pragma unroll
                for (int d = 0; d < 4; ++d){
                    *(unsigned short*)(Vb + (d*2)*240   + m*2) = (unsigned short)(arr[d] & 0xffffu);
                    *(unsigned short*)(Vb + (d*2+1)*240 + m*2) = (unsigned short)(arr[d] >> 16);
                }
            }
        }
        __syncthreads();
        #pragma unroll
        for (int mc = 0; mc < 7; ++mc){
            bh4 ka = *(const bh4*)(K1b + (mc*16 + col)*48 + g*8);
            bh4 kb = *(const bh4*)(K2b + (mc*16 + col)*48 + g*8);
            bh4 va = *(const bh4*)(VT1 + col*240 + mc*32 + g*8);
            bh4 vb = *(const bh4*)(VT2 + col*240 + mc*32 + g*8);
            #pragma unroll
            for (int nf = 0; nf < 2; ++nf){
                f32x4 zr = {0.f,0.f,0.f,0.f};
                f32x4 s1 = MFMA16x16(ka, qf[nf], zr);
                float p0 = exp2f(s1[0]*C2), p1 = exp2f(s1[1]*C2);
                float p2 = exp2f(s1[2]*C2), p3 = exp2f(s1[3]*C2);
                d1[nf] += (p0+p1)+(p2+p3);
                bh4 pf1 = __builtin_bit_cast(bh4, (uint2v){pk2rn(p0,p1), pk2rn(p2,p3)});
                o1[nf] = MFMA16x16(va, pf1, o1[nf]);
                f32x4 s2 = MFMA16x16(kb, qf[nf], zr);
                float r0 = exp2f(s2[0]*C2), r1 = exp2f(s2[1]*C2);
                float r2 = exp2f(s2[2]*C2), r3 = exp2f(s2[3]*C2);
                d2[nf] += (r0+r1)+(r2+r3);
                bh4 pf2 = __builtin_bit_cast(bh4, (uint2v){pk2rn(r0,r1), pk2rn(r2,r3)});
                o2[nf] = MFMA16x16(vb, pf2, o2[nf]);
            }
        }
    }
    #pragma unroll
    for (int nf = 0; nf < 2; ++nf){
        d1[nf] += __shfl_xor(d1[nf], 16, 64); d1[nf] += __shfl_xor(d1[nf], 32, 64);
        d2[nf] += __shfl_xor(d2[nf], 16, 64); d2[nf] += __shfl_xor(d2[nf], 32, 64);
    }
    if (g < 2){
        #pragma unroll
        for (int nf = 0; nf < 2; ++nf){
            if (nf == 1 && col >= 12) continue;
            int n = nseg*112 + w*28 + nf*16 + col;
            float ra = 1.f / d1[nf], rb = 1.f / d2[nf];
            float4 ov;
            ov.x = o1[nf][0]*ra + o2[nf][0]*rb;
            ov.y = o1[nf][1]*ra + o2[nf][1]*rb;
            ov.z = o1[nf][2]*ra + o2[nf][2]*rb;
            ov.w = o1[nf][3]*ra + o2[nf][3]*rb;
            *(float4*)(z + ((size_t)b*784 + n)*64 + h*8 + g*4) = ov;
        }
    }
}

// ---------------- kproj ----------------
__global__ __launch_bounds__(256) void kproj(const float* __restrict__ z,
    const float* __restrict__ pw, const float* __restrict__ pb,
    float* __restrict__ zc)
{
    __shared__ float zs[28*64];
    int blk = blockIdx.x;
    int b = blk / 28, hs = blk % 28;
    int t = threadIdx.x;
    const float* zrow = z + ((size_t)b*784 + hs*28)*64;
    for (int li = t; li < 1792; li += 256) zs[li] = zrow[li];
    __syncthreads();
    int c = t;
    float acc[28];
    float bias = pb[c];
    #pragma unroll
    for (int wsI = 0; wsI < 28; ++wsI) acc[wsI] = bias;
    for (int o = 0; o < 64; ++o){
        float wv = pw[o*256 + c];
        #pragma unroll
        for (int wsI = 0; wsI < 28; ++wsI) acc[wsI] = fmaf(zs[wsI*64+o], wv, acc[wsI]);
    }
    float* op = zc + (((size_t)(b*256 + c))*28 + hs)*28;
    #pragma unroll
    for (int f = 0; f < 7; ++f)
        ((float4*)op)[f] = make_float4(acc[4*f], acc[4*f+1], acc[4*f+2], acc[4*f+3]);
}

// ---------------- kups ----------------
__global__ __launch_bounds__(256) void kups(const float* __restrict__ zc, float* __restrict__ out)
{
    __shared__ float plane[784];
    __shared__ int   ti0[112];
    __shared__ float twv[112];
    int bc = blockIdx.x;
    int t = threadIdx.x;
    const float* src = zc + (size_t)bc*784;
    for (int li = t; li < 784; li += 256) plane[li] = src[li];
    if (t < 112){
        float s = (float)t * (27.f/111.f);
        int i0 = (int)s;
        if (i0 > 27) i0 = 27;
        ti0[t] = i0;
        twv[t] = s - (float)i0;
    }
    __syncthreads();
    float* op = out + (size_t)bc*12544;
    for (int i = t; i < 12544; i += 256){
        int y = i/112, xx = i%112;
        int y0 = ti0[y], x0 = ti0[xx];
        float wy = twv[y], wx = twv[xx];
        int y1 = min(y0+1, 27), x1 = min(x0+1, 27);
        const float* r0 = plane + y0*28;
        const float* r1 = plane + y1*28;
        float a  = r0[x0] + (r1[x0]-r0[x0])*wy;
        float bb = r0[x1] + (r1[x1]-r0[x1])*wy;
        op[i] = a + (bb-a)*wx;
    }
}

extern "C" void kernel_launch(void* const* d_in, const int* in_sizes, int n_in,
                              void* d_out, int out_size, void* d_ws, size_t ws_size,
                              hipStream_t stream) {
    const float* x   = (const float*)d_in[0];
    const float* srw = (const float*)d_in[1];
    const float* srb = (const float*)d_in[2];
    const float* lng = (const float*)d_in[3];
    const float* lnb = (const float*)d_in[4];
    const float* qw  = (const float*)d_in[5];
    const float* k1w = (const float*)d_in[6];
    const float* v1w = (const float*)d_in[7];
    const float* k2w = (const float*)d_in[8];
    const float* v2w = (const float*)d_in[9];
    const float* pw  = (const float*)d_in[10];
    const float* pb  = (const float*)d_in[11];

    char*  Rws  = (char*)d_ws;
    float* pws  = (float*)(Rws + 12845056);
    char*  srwb = Rws + 19267584;
    char*  Wtm  = Rws + 19791872;
    char*  Wta  = Rws + 19857408;
    char*  QWt  = Rws + 19922944;
    float* z    = (float*)(Rws + 12845056);   // aliases pws (dead after k2)
    float* zc   = z + 802816;
    float* out  = (float*)d_out;

    ktw  <<<137, 256, 0, stream>>>(srw, qw, k1w, v1w, k2w, v2w, srwb, Wtm, Wta, QWt);
    k1   <<<896, 512, 0, stream>>>(x, srwb, Rws, pws);
    k2   <<<448, 512, 0, stream>>>(pws, srb, lng, lnb, Wtm, Wta, QWt, Rws);
    kattn<<<896, 256, 0, stream>>>(Rws, z);
    kproj<<<448, 256, 0, stream>>>(z, pw, pb, zc);
    kups <<<4096, 256, 0, stream>>>(zc, out);
}

// Round 6
// 262.347 us; speedup vs baseline: 2.4639x; 1.0307x over previous
//
#include <hip/hip_runtime.h>
#include <math.h>

typedef __attribute__((ext_vector_type(8))) short short8;
typedef __attribute__((ext_vector_type(4))) short bh4;
typedef __attribute__((ext_vector_type(4))) float f32x4;
typedef __attribute__((ext_vector_type(2))) unsigned uint2v;

#define MFMA16(A,B,C) __builtin_amdgcn_mfma_f32_16x16x32_bf16(A,B,C,0,0,0)

#if __has_builtin(__builtin_amdgcn_mfma_f32_16x16x16bf16_1k)
#define MFMA16x16(A,B,C) __builtin_amdgcn_mfma_f32_16x16x16bf16_1k(A,B,C,0,0,0)
#else
__device__ __forceinline__ f32x4 mfma16x16_asm(bh4 a, bh4 b, f32x4 c){
    asm volatile("v_mfma_f32_16x16x16_bf16 %0, %1, %2, %0" : "+v"(c) : "v"(a), "v"(b));
    return c;
}
#define MFMA16x16(A,B,C) mfma16x16_asm(A,B,C)
#endif

__device__ __forceinline__ unsigned short f2b(float f){
    unsigned u = __builtin_bit_cast(unsigned, f);
    return (unsigned short)((u + 0x7fffu + ((u>>16)&1u)) >> 16);
}
__device__ __forceinline__ unsigned pk2(float a, float b){
    return (unsigned)f2b(a) | ((unsigned)f2b(b) << 16);
}
__device__ __forceinline__ unsigned pk2rn(float a, float b){
    unsigned ua = __builtin_bit_cast(unsigned, a) + 0x8000u;
    unsigned ub = __builtin_bit_cast(unsigned, b) + 0x8000u;
    return (ua >> 16) | (ub & 0xffff0000u);
}
__device__ __forceinline__ float b2f_lo(unsigned u){ return __builtin_bit_cast(float, u << 16); }
__device__ __forceinline__ float b2f_hi(unsigned u){ return __builtin_bit_cast(float, u & 0xffff0000u); }

// ---------------- ktw: one-time weight convert/transpose ----------------
__global__ __launch_bounds__(256) void ktw(const float* __restrict__ srw,
    const float* __restrict__ qw, const float* __restrict__ k1w,
    const float* __restrict__ v1w, const float* __restrict__ k2w,
    const float* __restrict__ v2w, char* __restrict__ srwb,
    char* __restrict__ Wtm, char* __restrict__ Wta, char* __restrict__ QWt)
{
    int blk = blockIdx.x, t = threadIdx.x;
    if (blk < 128){
        int base = blk*2048 + t*8;
        float4 a = *(const float4*)(srw + base);
        float4 b = *(const float4*)(srw + base + 4);
        uint4 u = { pk2(a.x,a.y), pk2(a.z,a.w), pk2(b.x,b.y), pk2(b.z,b.w) };
        *(uint4*)(srwb + (size_t)base*2) = u;
    } else if (blk < 136){
        __shared__ float T[256*33];
        int idx = blk - 128, fi = idx >> 1, half = idx & 1;
        const float* src = (fi==0) ? k1w : (fi==1) ? v1w : (fi==2) ? k2w : v2w;
        char* dst = ((fi < 2) ? Wtm : Wta) + (size_t)((fi & 1)*64 + half*32) * 512;
        for (int li = t; li < 8192; li += 256){
            int c = li >> 5, o = li & 31;
            T[c*33 + o] = src[c*64 + half*32 + o];
        }
        __syncthreads();
        for (int lo = t; lo < 1024; lo += 256){
            int o = lo >> 5, c8 = lo & 31;
            float v[8];
            #pragma unroll
            for (int k = 0; k < 8; ++k) v[k] = T[(c8*8 + k)*33 + o];
            uint4 u = { pk2(v[0],v[1]), pk2(v[2],v[3]), pk2(v[4],v[5]), pk2(v[6],v[7]) };
            *(uint4*)(dst + o*512 + c8*16) = u;
        }
    } else {
        __shared__ float T[64*65];
        for (int li = t; li < 4096; li += 256)
            T[(li >> 6)*65 + (li & 63)] = qw[li];
        __syncthreads();
        for (int lo = t; lo < 512; lo += 256){
            int o = lo >> 3, i8 = lo & 7;
            float v[8];
            #pragma unroll
            for (int k = 0; k < 8; ++k) v[k] = T[(i8*8 + k)*65 + o];
            uint4 u = { pk2(v[0],v[1]), pk2(v[2],v[3]), pk2(v[4],v[5]), pk2(v[6],v[7]) };
            *(uint4*)(QWt + o*128 + i8*16) = u;
        }
    }
}

// ---------------- k1: pipelined x stream -> pools + conv partials ----------------
// grid (b,hs,cgp) = 896 blocks, 512 threads; 1 barrier/iter, dbuf LDS + dbuf B-regs
__global__ __launch_bounds__(512) void k1(const float* __restrict__ x,
    const char* __restrict__ srwb, char* __restrict__ R, float* __restrict__ pws)
{
    __shared__ __align__(16) char Ab[2][32768];
    __shared__ float pm[2][924];
    __shared__ float pa[2][924];
    int blk = blockIdx.x;
    int b = blk / 56, r5 = blk % 56, hs = r5 >> 1, cgp = r5 & 1;
    int t = threadIdx.x;
    int w = t >> 6, l = t & 63, lr = l & 15, lg = l >> 4;
    int ofr = w & 3, mfr = w >> 2;
    int c0 = t / 28, p = t % 28;
    bool ldr = t < 448;
    f32x4 acc = {0.f,0.f,0.f,0.f};
    const char* Brow = srwb + (size_t)(ofr*16 + lr)*8192 + cgp*4096;
    size_t rowB = (size_t)b*784 + hs*28;
    const float* xpb = x + (size_t)(b*256 + cgp*128)*12544 + hs*4*112 + p*4;
    int swzp = (p & 7) << 4;
    int swzr = (lr & 7) << 4;

    float4 xr0[8], xr1[8];
    short8 bf0[16], bf1[16];

#define LOADX(XR, CI) do { if (ldr){ \
    const float* _s0 = xpb + (size_t)((CI)*32 + c0)*12544; \
    const float* _s1 = _s0 + (size_t)16*12544; \
    XR[0]=*(const float4*)(_s0);     XR[1]=*(const float4*)(_s0+112); \
    XR[2]=*(const float4*)(_s0+224); XR[3]=*(const float4*)(_s0+336); \
    XR[4]=*(const float4*)(_s1);     XR[5]=*(const float4*)(_s1+112); \
    XR[6]=*(const float4*)(_s1+224); XR[7]=*(const float4*)(_s1+336); } } while(0)

#define LOADB(BF, CI) do { _Pragma("unroll") \
    for (int ks = 0; ks < 16; ++ks) \
        BF[ks] = *(const short8*)(Brow + (CI)*1024 + ks*64 + lg*16); } while(0)

#define WRITEA(BUF, XR) do { if (ldr){ \
    _Pragma("unroll") \
    for (int kk = 0; kk < 2; ++kk){ \
        float4 v0 = XR[kk*4+0], v1 = XR[kk*4+1], v2 = XR[kk*4+2], v3 = XR[kk*4+3]; \
        float mx = fmaxf(fmaxf(fmaxf(v0.x,v0.y),fmaxf(v0.z,v0.w)), \
                         fmaxf(fmaxf(v1.x,v1.y),fmaxf(v1.z,v1.w))); \
        mx = fmaxf(mx, fmaxf(fmaxf(fmaxf(v2.x,v2.y),fmaxf(v2.z,v2.w)), \
                             fmaxf(fmaxf(v3.x,v3.y),fmaxf(v3.z,v3.w)))); \
        float sm = (v0.x+v0.y+v0.z+v0.w)+(v1.x+v1.y+v1.z+v1.w) \
                 + (v2.x+v2.y+v2.z+v2.w)+(v3.x+v3.y+v3.z+v3.w); \
        int c = c0 + kk*16; \
        pm[BUF][p*33 + c] = mx; \
        pa[BUF][p*33 + c] = sm * (1.f/16.f); \
        char* Ap = Ab[BUF] + p*1024; \
        *(uint2*)(Ap + ((c*32 +  0) ^ swzp)) = (uint2){ pk2(v0.x,v0.y), pk2(v0.z,v0.w) }; \
        *(uint2*)(Ap + ((c*32 +  8) ^ swzp)) = (uint2){ pk2(v1.x,v1.y), pk2(v1.z,v1.w) }; \
        *(uint2*)(Ap + ((c*32 + 16) ^ swzp)) = (uint2){ pk2(v2.x,v2.y), pk2(v2.z,v2.w) }; \
        *(uint2*)(Ap + ((c*32 + 24) ^ swzp)) = (uint2){ pk2(v3.x,v3.y), pk2(v3.z,v3.w) }; \
    } } } while(0)

#define POOLW(BUF, CI) do { if (t < 112){ \
    int m_ = t >> 2, c8 = t & 3; \
    float vm[8], va8[8]; \
    _Pragma("unroll") \
    for (int kq = 0; kq < 8; ++kq){ \
        vm[kq]  = pm[BUF][m_*33 + c8*8 + kq]; \
        va8[kq] = pa[BUF][m_*33 + c8*8 + kq]; } \
    uint4 um = { pk2(vm[0],vm[1]), pk2(vm[2],vm[3]), pk2(vm[4],vm[5]), pk2(vm[6],vm[7]) }; \
    uint4 ua = { pk2(va8[0],va8[1]), pk2(va8[2],va8[3]), pk2(va8[4],va8[5]), pk2(va8[6],va8[7]) }; \
    int cg = cgp*4 + (CI); \
    *(uint4*)(R + (rowB + m_)*1024 + cg*64 + c8*16)       = um; \
    *(uint4*)(R + (rowB + m_)*1024 + 512 + cg*64 + c8*16) = ua; } } while(0)

#define MFMAPH(BUF, BF) do { \
    const char* Arow = Ab[BUF] + (mfr*16 + lr)*1024; \
    _Pragma("unroll") \
    for (int ks = 0; ks < 16; ++ks){ \
        short8 a = *(const short8*)(Arow + ((ks*64 + lg*16) ^ swzr)); \
        acc = MFMA16(a, BF[ks], acc); } } while(0)

    LOADX(xr0, 0); LOADB(bf0, 0);

    WRITEA(0, xr0);
    LOADX(xr1, 1); LOADB(bf1, 1);
    __syncthreads();
    POOLW(0, 0); MFMAPH(0, bf0);

    WRITEA(1, xr1);
    LOADX(xr0, 2); LOADB(bf0, 2);
    __syncthreads();
    POOLW(1, 1); MFMAPH(1, bf1);

    WRITEA(0, xr0);
    LOADX(xr1, 3); LOADB(bf1, 3);
    __syncthreads();
    POOLW(0, 2); MFMAPH(0, bf0);

    WRITEA(1, xr1);
    __syncthreads();
    POOLW(1, 3); MFMAPH(1, bf1);

#undef LOADX
#undef LOADB
#undef WRITEA
#undef POOLW
#undef MFMAPH

    float* pp = pws + (size_t)((b*28 + hs)*2 + cgp)*1792;
    #pragma unroll
    for (int rg = 0; rg < 4; ++rg){
        int m = mfr*16 + lg*4 + rg;
        if (m < 28) pp[m*64 + ofr*16 + lr] = acc[rg];
    }
}

// ---------------- k2: partial-sum + LN + qGEMM + pool GEMMs ----------------
__global__ __launch_bounds__(512) void k2(const float* __restrict__ pws_,
    const float* __restrict__ srb, const float* __restrict__ lng,
    const float* __restrict__ lnb, const char* __restrict__ Wtm,
    const char* __restrict__ Wta, const char* __restrict__ QWt,
    char* __restrict__ R)
{
    __shared__ __align__(16) char PM[16384];
    __shared__ __align__(16) char PA[16384];
    __shared__ float Db[32*64];
    __shared__ __align__(16) char QN[4096];
    int blk = blockIdx.x, b = blk/28, hs = blk%28;
    int t = threadIdx.x, w = t>>6, l = t&63, lr = l&15, lg = l>>4;
    size_t rowB = (size_t)b*784 + hs*28;
    const char* Rb = R + rowB*1024;
    for (int li = t; li < 896; li += 512){
        int m = li >> 5, c16 = li & 31;
        uint4 vm = *(const uint4*)(Rb + (size_t)m*1024 + c16*16);
        uint4 va = *(const uint4*)(Rb + (size_t)m*1024 + 512 + c16*16);
        int dst = m*512 + ((c16*16) ^ ((m&7)<<4));
        *(uint4*)(PM + dst) = vm;
        *(uint4*)(PA + dst) = va;
    }
    const float* p0 = pws_ + (size_t)(b*28 + hs)*2*1792;
    const float* p1 = p0 + 1792;
    for (int e = t; e < 1792; e += 512)
        Db[e] = p0[e] + p1[e] + srb[e & 63];
    __syncthreads();
    float g = lng[l], be = lnb[l];
    #pragma unroll
    for (int i = 0; i < 4; ++i){
        int m = w + i*8;
        float v = Db[m*64 + l];
        float s = v, ss = v*v;
        #pragma unroll
        for (int off = 1; off < 64; off <<= 1){
            s  += __shfl_xor(s,  off, 64);
            ss += __shfl_xor(ss, off, 64);
        }
        float mu = s * (1.f/64.f);
        float var = ss * (1.f/64.f) - mu*mu;
        float qn = (v - mu) * rsqrtf(var + 1e-5f) * g + be;
        *(unsigned short*)(QN + m*128 + ((l*2) ^ ((m&7)<<4))) = f2b(qn);
    }
    __syncthreads();
    int fam = w >> 2, ofp = w & 3;
    const char* PMA = fam ? PA : PM;
    const char* Wt  = fam ? Wta : Wtm;
    f32x4 a00={0.f,0.f,0.f,0.f}, a01=a00, a10=a00, a11=a00;
    int swzr = (lr & 7) << 4;
    #pragma unroll
    for (int ks = 0; ks < 8; ++ks){
        int kb = ks*64 + lg*16;
        short8 x0 = *(const short8*)(PMA + lr*512 + (kb ^ swzr));
        short8 x1 = *(const short8*)(PMA + (16+lr)*512 + (kb ^ swzr));
        short8 b0 = *(const short8*)(Wt + (size_t)(ofp*32 + lr)*512 + kb);
        short8 b1 = *(const short8*)(Wt + (size_t)(ofp*32 + 16 + lr)*512 + kb);
        a00 = MFMA16(x0, b0, a00); a01 = MFMA16(x0, b1, a01);
        a10 = MFMA16(x1, b0, a10); a11 = MFMA16(x1, b1, a11);
    }
    f32x4 q0={0.f,0.f,0.f,0.f}, q1=q0;
    if (w < 4){
        #pragma unroll
        for (int ks = 0; ks < 2; ++ks){
            int kb = ks*64 + lg*16;
            short8 xa_ = *(const short8*)(QN + lr*128 + (kb ^ swzr));
            short8 xb_ = *(const short8*)(QN + (16+lr)*128 + (kb ^ swzr));
            short8 bq  = *(const short8*)(QWt + (size_t)(w*16 + lr)*128 + kb);
            q0 = MFMA16(xa_, bq, q0);
            q1 = MFMA16(xb_, bq, q1);
        }
    }
    #pragma unroll
    for (int j = 0; j < 2; ++j){
        int o128 = ofp*32 + j*16 + lr;
        int o = o128 & 63, hh = o >> 3, dd = o & 7, mat = fam*2 + (o128 >> 6);
        int byteoff = 128 + hh*64 + mat*16 + dd*2;
        f32x4 am  = j ? a01 : a00;
        f32x4 am1 = j ? a11 : a10;
        #pragma unroll
        for (int rg = 0; rg < 4; ++rg){
            int m0 = lg*4 + rg, m1 = 16 + lg*4 + rg;
            *(unsigned short*)(R + (rowB + m0)*1024 + byteoff) = f2b(am[rg]);
            if (m1 < 28)
                *(unsigned short*)(R + (rowB + m1)*1024 + byteoff) = f2b(am1[rg]);
        }
    }
    if (w < 4){
        int o = w*16 + lr;
        #pragma unroll
        for (int rg = 0; rg < 4; ++rg){
            int m0 = lg*4 + rg, m1 = 16 + lg*4 + rg;
            *(unsigned short*)(R + (rowB + m0)*1024 + o*2) = f2b(q0[rg]);
            if (m1 < 28)
                *(unsigned short*)(R + (rowB + m1)*1024 + o*2) = f2b(q1[rg]);
        }
    }
}

// ---------------- kattn: MFMA dual attention (swapped-operand, hd=8 pad 16) ----------------
__global__ __launch_bounds__(256) void kattn(const char* __restrict__ R, float* __restrict__ z)
{
    __shared__ __align__(16) char QT [6144];
    __shared__ __align__(16) char K1b[5376];
    __shared__ __align__(16) char K2b[5376];
    __shared__ __align__(16) char VT1[3840];
    __shared__ __align__(16) char VT2[3840];
    int blk = blockIdx.x;
    int bh = blk / 7, nseg = blk % 7;
    int b = bh >> 3, h = bh & 7;
    int t = threadIdx.x, w = t >> 6, l = t & 63;
    int col = l & 15, g = l >> 4;

    for (int i = t; i < 384; i += 256) ((uint4*)QT)[i] = uint4{0,0,0,0};
    for (int i = t; i < 112; i += 256){
        *(uint4*)(K1b + i*48 + 16) = uint4{0,0,0,0};
        *(uint4*)(K2b + i*48 + 16) = uint4{0,0,0,0};
    }
    for (int i = t; i < 120; i += 256){
        *(uint4*)(VT1 + 1920 + i*16) = uint4{0,0,0,0};
        *(uint4*)(VT2 + 1920 + i*16) = uint4{0,0,0,0};
    }
    __syncthreads();
    if (t < 112){
        uint4 qv = *(const uint4*)(R + ((size_t)b*784 + nseg*112 + t)*1024 + h*16);
        *(uint2*)(QT + t*48)     = uint2{qv.x, qv.y};
        *(uint2*)(QT + t*48 + 8) = uint2{qv.z, qv.w};
    }
    __syncthreads();

    bh4 qf[2];
    #pragma unroll
    for (int nf = 0; nf < 2; ++nf)
        qf[nf] = *(const bh4*)(QT + (w*28 + nf*16 + col)*48 + g*8);

    f32x4 o1[2] = {{0,0,0,0},{0,0,0,0}}, o2[2] = {{0,0,0,0},{0,0,0,0}};
    float d1[2] = {0.f,0.f}, d2[2] = {0.f,0.f};
    const float C2 = 0.51004244f;

    for (int mt = 0; mt < 7; ++mt){
        __syncthreads();
        for (int li = t; li < 448; li += 256){
            int m = li >> 2, part = li & 3;
            uint4 v = *(const uint4*)(R + ((size_t)b*784 + mt*112 + m)*1024 + 128 + h*64 + part*16);
            if ((part & 1) == 0){
                char* Kb = (part == 0) ? K1b : K2b;
                *(uint2*)(Kb + m*48)     = uint2{v.x, v.y};
                *(uint2*)(Kb + m*48 + 8) = uint2{v.z, v.w};
            } else {
                char* Vb = (part == 1) ? VT1 : VT2;
                unsigned arr[4] = {v.x, v.y, v.z, v.w};
                #pragma unroll
                for (int d = 0; d < 4; ++d){
                    *(unsigned short*)(Vb + (d*2)*240   + m*2) = (unsigned short)(arr[d] & 0xffffu);
                    *(unsigned short*)(Vb + (d*2+1)*240 + m*2) = (unsigned short)(arr[d] >> 16);
                }
            }
        }
        __syncthreads();
        #pragma unroll
        for (int mc = 0; mc < 7; ++mc){
            bh4 ka = *(const bh4*)(K1b + (mc*16 + col)*48 + g*8);
            bh4 kb = *(const bh4*)(K2b + (mc*16 + col)*48 + g*8);
            bh4 va = *(const bh4*)(VT1 + col*240 + mc*32 + g*8);
            bh4 vb = *(const bh4*)(VT2 + col*240 + mc*32 + g*8);
            #pragma unroll
            for (int nf = 0; nf < 2; ++nf){
                f32x4 zr = {0.f,0.f,0.f,0.f};
                f32x4 s1 = MFMA16x16(ka, qf[nf], zr);
                float p0 = exp2f(s1[0]*C2), p1 = exp2f(s1[1]*C2);
                float p2 = exp2f(s1[2]*C2), p3 = exp2f(s1[3]*C2);
                d1[nf] += (p0+p1)+(p2+p3);
                bh4 pf1 = __builtin_bit_cast(bh4, (uint2v){pk2rn(p0,p1), pk2rn(p2,p3)});
                o1[nf] = MFMA16x16(va, pf1, o1[nf]);
                f32x4 s2 = MFMA16x16(kb, qf[nf], zr);
                float r0 = exp2f(s2[0]*C2), r1 = exp2f(s2[1]*C2);
                float r2 = exp2f(s2[2]*C2), r3 = exp2f(s2[3]*C2);
                d2[nf] += (r0+r1)+(r2+r3);
                bh4 pf2 = __builtin_bit_cast(bh4, (uint2v){pk2rn(r0,r1), pk2rn(r2,r3)});
                o2[nf] = MFMA16x16(vb, pf2, o2[nf]);
            }
        }
    }
    #pragma unroll
    for (int nf = 0; nf < 2; ++nf){
        d1[nf] += __shfl_xor(d1[nf], 16, 64); d1[nf] += __shfl_xor(d1[nf], 32, 64);
        d2[nf] += __shfl_xor(d2[nf], 16, 64); d2[nf] += __shfl_xor(d2[nf], 32, 64);
    }
    if (g < 2){
        #pragma unroll
        for (int nf = 0; nf < 2; ++nf){
            if (nf == 1 && col >= 12) continue;
            int n = nseg*112 + w*28 + nf*16 + col;
            float ra = 1.f / d1[nf], rb = 1.f / d2[nf];
            float4 ov;
            ov.x = o1[nf][0]*ra + o2[nf][0]*rb;
            ov.y = o1[nf][1]*ra + o2[nf][1]*rb;
            ov.z = o1[nf][2]*ra + o2[nf][2]*rb;
            ov.w = o1[nf][3]*ra + o2[nf][3]*rb;
            *(float4*)(z + ((size_t)b*784 + n)*64 + h*8 + g*4) = ov;
        }
    }
}

// ---------------- kproj ----------------
__global__ __launch_bounds__(256) void kproj(const float* __restrict__ z,
    const float* __restrict__ pw, const float* __restrict__ pb,
    float* __restrict__ zc)
{
    __shared__ float zs[28*64];
    int blk = blockIdx.x;
    int b = blk / 28, hs = blk % 28;
    int t = threadIdx.x;
    const float* zrow = z + ((size_t)b*784 + hs*28)*64;
    for (int li = t; li < 1792; li += 256) zs[li] = zrow[li];
    __syncthreads();
    int c = t;
    float acc[28];
    float bias = pb[c];
    #pragma unroll
    for (int wsI = 0; wsI < 28; ++wsI) acc[wsI] = bias;
    for (int o = 0; o < 64; ++o){
        float wv = pw[o*256 + c];
        #pragma unroll
        for (int wsI = 0; wsI < 28; ++wsI) acc[wsI] = fmaf(zs[wsI*64+o], wv, acc[wsI]);
    }
    float* op = zc + (((size_t)(b*256 + c))*28 + hs)*28;
    #pragma unroll
    for (int f = 0; f < 7; ++f)
        ((float4*)op)[f] = make_float4(acc[4*f], acc[4*f+1], acc[4*f+2], acc[4*f+3]);
}

// ---------------- kups ----------------
__global__ __launch_bounds__(256) void kups(const float* __restrict__ zc, float* __restrict__ out)
{
    __shared__ float plane[784];
    __shared__ int   ti0[112];
    __shared__ float twv[112];
    int bc = blockIdx.x;
    int t = threadIdx.x;
    const float* src = zc + (size_t)bc*784;
    for (int li = t; li < 784; li += 256) plane[li] = src[li];
    if (t < 112){
        float s = (float)t * (27.f/111.f);
        int i0 = (int)s;
        if (i0 > 27) i0 = 27;
        ti0[t] = i0;
        twv[t] = s - (float)i0;
    }
    __syncthreads();
    float* op = out + (size_t)bc*12544;
    for (int i = t; i < 12544; i += 256){
        int y = i/112, xx = i%112;
        int y0 = ti0[y], x0 = ti0[xx];
        float wy = twv[y], wx = twv[xx];
        int y1 = min(y0+1, 27), x1 = min(x0+1, 27);
        const float* r0 = plane + y0*28;
        const float* r1 = plane + y1*28;
        float a  = r0[x0] + (r1[x0]-r0[x0])*wy;
        float bb = r0[x1] + (r1[x1]-r0[x1])*wy;
        op[i] = a + (bb-a)*wx;
    }
}

extern "C" void kernel_launch(void* const* d_in, const int* in_sizes, int n_in,
                              void* d_out, int out_size, void* d_ws, size_t ws_size,
                              hipStream_t stream) {
    const float* x   = (const float*)d_in[0];
    const float* srw = (const float*)d_in[1];
    const float* srb = (const float*)d_in[2];
    const float* lng = (const float*)d_in[3];
    const float* lnb = (const float*)d_in[4];
    const float* qw  = (const float*)d_in[5];
    const float* k1w = (const float*)d_in[6];
    const float* v1w = (const float*)d_in[7];
    const float* k2w = (const float*)d_in[8];
    const float* v2w = (const float*)d_in[9];
    const float* pw  = (const float*)d_in[10];
    const float* pb  = (const float*)d_in[11];

    char*  Rws  = (char*)d_ws;
    float* pws  = (float*)(Rws + 12845056);
    char*  srwb = Rws + 19267584;
    char*  Wtm  = Rws + 19791872;
    char*  Wta  = Rws + 19857408;
    char*  QWt  = Rws + 19922944;
    float* z    = (float*)(Rws + 12845056);   // aliases pws (dead after k2)
    float* zc   = z + 802816;
    float* out  = (float*)d_out;

    ktw  <<<137, 256, 0, stream>>>(srw, qw, k1w, v1w, k2w, v2w, srwb, Wtm, Wta, QWt);
    k1   <<<896, 512, 0, stream>>>(x, srwb, Rws, pws);
    k2   <<<448, 512, 0, stream>>>(pws, srb, lng, lnb, Wtm, Wta, QWt, Rws);
    kattn<<<896, 256, 0, stream>>>(Rws, z);
    kproj<<<448, 256, 0, stream>>>(z, pw, pb, zc);
    kups <<<4096, 256, 0, stream>>>(zc, out);
}